// Round 6
// baseline (8746.690 us; speedup 1.0000x reference)
//
#include <hip/hip_runtime.h>

#define HH 128
constexpr int cN   = 200000;
constexpr int cE   = 800000;
constexpr int cNS  = 400000;
constexpr int cES  = 1600000;
constexpr int cB   = 512;
constexpr int cPPG = 8;
constexpr int cPT  = 4;
constexpr int cNP  = cB * cPPG;     // 4096 patches
constexpr int cNF  = 64;
constexpr int cNE  = 16;
constexpr int cRW  = 16;
constexpr int cPRW = 16;
constexpr int cL   = 4;

__device__ __forceinline__ float b2f(unsigned short b) {
    return __uint_as_float(((unsigned int)b) << 16);
}
__device__ __forceinline__ unsigned short f2b(float f) {
    unsigned int u = __float_as_uint(f);
    return (unsigned short)((u + 0x7fffu + ((u >> 16) & 1u)) >> 16);  // RNE
}

// ---------------- diagnostic ----------------
__global__ void k_diag(float* __restrict__ out, int n, float val) {
    int gid = blockIdx.x * 256 + threadIdx.x;
    if (gid < n) out[gid] = val;
}

__global__ void k_zero_int(int* __restrict__ p, int n) {
    int i = blockIdx.x * 256 + threadIdx.x;
    if (i < n) p[i] = 0;
}
__global__ void k_copy_int(const int* __restrict__ a, int* __restrict__ b, int n) {
    int i = blockIdx.x * 256 + threadIdx.x;
    if (i < n) b[i] = a[i];
}

// ---------------- CSR build ----------------
__global__ void k_hist(const int* __restrict__ dst, int* __restrict__ cnt, int ne) {
    int e = blockIdx.x * 256 + threadIdx.x;
    if (e < ne) atomicAdd(&cnt[dst[e]], 1);
}

__global__ void k_scan_local(const int* __restrict__ cnt, int* __restrict__ rp1,
                             int* __restrict__ bsum, int n) {
    __shared__ int s[256];
    int t = threadIdx.x;
    int i = blockIdx.x * 256 + t;
    s[t] = (i < n) ? cnt[i] : 0;
    __syncthreads();
    for (int off = 1; off < 256; off <<= 1) {
        int u = (t >= off) ? s[t - off] : 0;
        __syncthreads();
        s[t] += u;
        __syncthreads();
    }
    if (i < n) rp1[i] = s[t];
    if (t == 255) bsum[blockIdx.x] = s[255];
}

__global__ void k_scan_bsums(int* __restrict__ bsum, int nb) {
    __shared__ int s[256];
    __shared__ int carry;
    int t = threadIdx.x;
    if (t == 0) carry = 0;
    __syncthreads();
    for (int base = 0; base < nb; base += 256) {
        int i = base + t;
        s[t] = (i < nb) ? bsum[i] : 0;
        __syncthreads();
        for (int off = 1; off < 256; off <<= 1) {
            int u = (t >= off) ? s[t - off] : 0;
            __syncthreads();
            s[t] += u;
            __syncthreads();
        }
        int c = carry;
        if (i < nb) bsum[i] = s[t] + c;
        __syncthreads();
        if (t == 0) carry = c + s[255];
        __syncthreads();
    }
}

__global__ void k_rp_finalize(const int* __restrict__ bsum, int* __restrict__ rp, int n) {
    int i = blockIdx.x * 256 + threadIdx.x;
    if (i == 0) rp[0] = 0;
    if (i < n) {
        int blk = i >> 8;
        rp[i + 1] += blk ? bsum[blk - 1] : 0;
    }
}

// scatter edges into dst-sorted order; also record dst row per slot
__global__ void k_scatter(const int* __restrict__ src, const int* __restrict__ dst,
                          const int* __restrict__ emap, int* __restrict__ cursor,
                          int* __restrict__ srcs, int* __restrict__ ais,
                          int* __restrict__ dsts, int ne) {
    int e = blockIdx.x * 256 + threadIdx.x;
    if (e >= ne) return;
    int d = dst[e];
    int p = atomicAdd(&cursor[d], 1);
    srcs[p] = src[e];
    ais[p] = emap ? emap[e] : e;
    dsts[p] = d;
}

// ---------------- node encoder: x0 = x@Win + bin + rw@Wrw + brw (f32 out) ----------------
__global__ void k_node_encode(const float* __restrict__ x, const float* __restrict__ rw,
                              const float* __restrict__ Win, const float* __restrict__ bin,
                              const float* __restrict__ Wrw, const float* __restrict__ brw,
                              float* __restrict__ x0) {
    __shared__ float sx[cNF];
    __shared__ float srw[cRW];
    int node = blockIdx.x;
    int t = threadIdx.x;  // 128
    if (t < cNF) sx[t] = x[(size_t)node * cNF + t];
    else if (t < cNF + cRW) srw[t - cNF] = rw[(size_t)node * cRW + (t - cNF)];
    __syncthreads();
    float acc = bin[t] + brw[t];
#pragma unroll
    for (int k = 0; k < cNF; k++) acc += sx[k] * Win[k * HH + t];
#pragma unroll
    for (int k = 0; k < cRW; k++) acc += srw[k] * Wrw[k * HH + t];
    x0[(size_t)node * HH + t] = acc;
}

// encoder fused with row gather, bf16 out
__global__ void k_encode_gather_bf16(const float* __restrict__ x, const float* __restrict__ rw,
                                     const int* __restrict__ map,
                                     const float* __restrict__ Win, const float* __restrict__ bin,
                                     const float* __restrict__ Wrw, const float* __restrict__ brw,
                                     unsigned short* __restrict__ out) {
    __shared__ float sx[cNF];
    __shared__ float srw[cRW];
    int node = map[blockIdx.x];
    int t = threadIdx.x;  // 128
    if (t < cNF) sx[t] = x[(size_t)node * cNF + t];
    else if (t < cNF + cRW) srw[t - cNF] = rw[(size_t)node * cRW + (t - cNF)];
    __syncthreads();
    float acc = bin[t] + brw[t];
#pragma unroll
    for (int k = 0; k < cNF; k++) acc += sx[k] * Win[k * HH + t];
#pragma unroll
    for (int k = 0; k < cRW; k++) acc += srw[k] * Wrw[k * HH + t];
    out[(size_t)blockIdx.x * HH + t] = f2b(acc);
}

// ---------------- fused layer: edge-parallel LDS-atomic agg + GEMM, ping-pong h ----------------
// h_new = relu(concat(h_old, agg) @ W + b)
// agg[r] = sum_{e: dst=r} (h_old[src_e] + relu(ea_e@We+be)) * w_e   (f32, LDS atomics)
template <bool BF16>
__global__ void __launch_bounds__(256)
k_layer_fused(const void* __restrict__ h_in_v, void* __restrict__ h_out_v,
              const int* __restrict__ rp, const int* __restrict__ srcs,
              const int* __restrict__ ais, const int* __restrict__ dsts,
              const float* __restrict__ eattr, const float* __restrict__ ew,
              const float* __restrict__ We, const float* __restrict__ be,
              const float* __restrict__ W, const float* __restrict__ b) {
    __shared__ float a[32][2 * HH];  // 32 KB
    int base = blockIdx.x * 32;
    int t = threadIdx.x;  // 256
    const float* hf = (const float*)h_in_v;
    const unsigned short* hb = (const unsigned short*)h_in_v;

    // A1: stage own h rows into a[r][0..127], zero agg half a[r][128..255]
    for (int i = t; i < 32 * HH; i += 256) {
        int r = i >> 7, c = i & 127;
        size_t idx = (size_t)(base + r) * HH + c;
        a[r][c] = BF16 ? b2f(hb[idx]) : hf[idx];
        a[r][HH + c] = 0.f;
    }
    __syncthreads();

    // A2: edge-parallel over the block's contiguous dst-sorted edge range.
    // Two 128-thread groups; each group processes one edge per iteration
    // (lane covers channel c). No loop-carried deps -> full MLP.
    {
        int c = t & 127;
        int estart = rp[base], eend = rp[base + 32];
        for (int e = estart + (t >> 7); e < eend; e += 2) {
            int s = srcs[e];
            int ai = ais[e];
            int d = dsts[e] - base;
            float w = ew[ai];
            const float* ea = eattr + (size_t)ai * cNE;
            float eh = be[c];
#pragma unroll
            for (int k = 0; k < cNE; k++) eh += ea[k] * We[k * HH + c];
            eh = fmaxf(eh, 0.f);
            float hv = BF16 ? b2f(hb[(size_t)s * HH + c]) : hf[(size_t)s * HH + c];
            atomicAdd(&a[d][HH + c], (hv + eh) * w);
        }
    }
    __syncthreads();

    // B: 32x128 GEMM, 4x4 per thread
    int cg = t & 31;   // cols cg*4..+3
    int rg = t >> 5;   // rows rg*4..+3
    float acc[4][4];
#pragma unroll
    for (int r = 0; r < 4; r++)
#pragma unroll
        for (int c = 0; c < 4; c++) acc[r][c] = 0.f;
    for (int k = 0; k < 2 * HH; k += 4) {
        float4 av[4];
#pragma unroll
        for (int r = 0; r < 4; r++) av[r] = *(const float4*)&a[rg * 4 + r][k];
        float4 wv[4];
#pragma unroll
        for (int kk = 0; kk < 4; kk++) wv[kk] = *(const float4*)&W[(size_t)(k + kk) * HH + cg * 4];
#pragma unroll
        for (int r = 0; r < 4; r++) {
            float a0 = av[r].x, a1 = av[r].y, a2 = av[r].z, a3 = av[r].w;
            acc[r][0] += a0 * wv[0].x + a1 * wv[1].x + a2 * wv[2].x + a3 * wv[3].x;
            acc[r][1] += a0 * wv[0].y + a1 * wv[1].y + a2 * wv[2].y + a3 * wv[3].y;
            acc[r][2] += a0 * wv[0].z + a1 * wv[1].z + a2 * wv[2].z + a3 * wv[3].z;
            acc[r][3] += a0 * wv[0].w + a1 * wv[1].w + a2 * wv[2].w + a3 * wv[3].w;
        }
    }
    float4 bv = *(const float4*)&b[cg * 4];
#pragma unroll
    for (int r = 0; r < 4; r++) {
        int row = base + rg * 4 + r;
        float o0 = fmaxf(acc[r][0] + bv.x, 0.f);
        float o1 = fmaxf(acc[r][1] + bv.y, 0.f);
        float o2 = fmaxf(acc[r][2] + bv.z, 0.f);
        float o3 = fmaxf(acc[r][3] + bv.w, 0.f);
        if (BF16) {
            ushort4 o = { f2b(o0), f2b(o1), f2b(o2), f2b(o3) };
            *(ushort4*)&((unsigned short*)h_out_v)[(size_t)row * HH + cg * 4] = o;
        } else {
            float4 o = { o0, o1, o2, o3 };
            *(float4*)&((float*)h_out_v)[(size_t)row * HH + cg * 4] = o;
        }
    }
}

// ---------------- segmented mean over sorted batch ----------------
__global__ void k_seg_mean_f32(const float* __restrict__ src, const int* __restrict__ map,
                               const int* __restrict__ batch, float* __restrict__ out, int nrows) {
    int b = blockIdx.x;
    int t = threadIdx.x;  // 128
    int lo = 0, hi = nrows;
    while (lo < hi) { int m = (lo + hi) >> 1; if (batch[m] < b) lo = m + 1; else hi = m; }
    int s = lo;
    hi = nrows;
    while (lo < hi) { int m = (lo + hi) >> 1; if (batch[m] < b + 1) lo = m + 1; else hi = m; }
    int e = lo;
    float acc = 0.f;
    for (int r = s; r < e; r++) {
        size_t row = map ? (size_t)map[r] : (size_t)r;
        acc += src[row * HH + t];
    }
    out[(size_t)b * HH + t] = acc / fmaxf((float)(e - s), 1.f);
}

__global__ void k_seg_mean_bf16(const unsigned short* __restrict__ src,
                                const int* __restrict__ batch, float* __restrict__ out, int nrows) {
    int b = blockIdx.x;
    int t = threadIdx.x;  // 128
    int lo = 0, hi = nrows;
    while (lo < hi) { int m = (lo + hi) >> 1; if (batch[m] < b) lo = m + 1; else hi = m; }
    int s = lo;
    hi = nrows;
    while (lo < hi) { int m = (lo + hi) >> 1; if (batch[m] < b + 1) lo = m + 1; else hi = m; }
    int e = lo;
    float acc = 0.f;
    for (int r = s; r < e; r++) acc += b2f(src[(size_t)r * HH + t]);
    out[(size_t)b * HH + t] = acc / fmaxf((float)(e - s), 1.f);
}

// ---------------- head kernels ----------------
__global__ void k_cond(const float* __restrict__ mctx, const float* __restrict__ mtgt,
                       const int* __restrict__ cidx, const int* __restrict__ tgt_idxs,
                       const float* __restrict__ ppe, const float* __restrict__ Wprw,
                       const float* __restrict__ bprw, float* __restrict__ cond,
                       float* __restrict__ out0) {
    int r = blockIdx.x;   // 0..2047
    int t = threadIdx.x;  // 128
    int bg = r >> 2, tt = r & 3;
    int ti = tgt_idxs[bg * cPT + tt] + bg * cPPG;
    int ci = cidx[bg] + bg * cPPG;
    __shared__ float pe[cPRW];
    if (t < cPRW) pe[t] = ppe[(size_t)ti * cPRW + t];
    __syncthreads();
    float acc = bprw[t];
#pragma unroll
    for (int k = 0; k < cPRW; k++) acc += pe[k] * Wprw[k * HH + t];
    cond[(size_t)r * HH + t] = mctx[(size_t)ci * HH + t] + acc;
    out0[(size_t)r * HH + t] = mtgt[(size_t)ti * HH + t];
}

__global__ void k_gemm_h(const float* __restrict__ x, const float* __restrict__ W,
                         const float* __restrict__ b, float* __restrict__ y) {
    int r = blockIdx.x;
    int t = threadIdx.x;  // 128
    __shared__ float xr[HH];
    xr[t] = x[(size_t)r * HH + t];
    __syncthreads();
    float acc = b[t];
#pragma unroll 8
    for (int k = 0; k < HH; k++) acc += xr[k] * W[k * HH + t];
    y[(size_t)r * HH + t] = acc;
}

__global__ void k_bn_stats(const float* __restrict__ x, float* __restrict__ stats, int rows) {
    int c = blockIdx.x;
    int t = threadIdx.x;  // 256
    float s = 0.f, sq = 0.f;
    for (int r = t; r < rows; r += 256) {
        float v = x[(size_t)r * HH + c];
        s += v; sq += v * v;
    }
    __shared__ float bs[256], bq[256];
    bs[t] = s; bq[t] = sq;
    __syncthreads();
    for (int o = 128; o > 0; o >>= 1) {
        if (t < o) { bs[t] += bs[t + o]; bq[t] += bq[t + o]; }
        __syncthreads();
    }
    if (t == 0) {
        float m = bs[0] / rows;
        float var = bq[0] / rows - m * m;
        stats[c] = m;
        stats[HH + c] = rsqrtf(var + 1e-5f);
    }
}

__global__ void k_bn_relu(float* __restrict__ x, const float* __restrict__ stats,
                          const float* __restrict__ g, const float* __restrict__ be, int rows) {
    int gid = blockIdx.x * 256 + threadIdx.x;
    if (gid >= rows * HH) return;
    int c = gid & 127;
    float v = (x[gid] - stats[c]) * stats[HH + c] * g[c] + be[c];
    x[gid] = fmaxf(v, 0.f);
}

// ---------------- CSR build driver ----------------
static void build_csr(const int* src, const int* dst, const int* emap, int nnodes, int ne,
                      int* rp, int* srcs, int* ais, int* dsts, int* cursor, int* bsum,
                      hipStream_t stream) {
    int nb = (nnodes + 255) / 256;
    k_zero_int<<<nb, 256, 0, stream>>>(cursor, nnodes);          // cursor doubles as cnt
    k_hist<<<(ne + 255) / 256, 256, 0, stream>>>(dst, cursor, ne);
    k_scan_local<<<nb, 256, 0, stream>>>(cursor, rp + 1, bsum, nnodes);
    k_scan_bsums<<<1, 256, 0, stream>>>(bsum, nb);
    k_rp_finalize<<<nb, 256, 0, stream>>>(bsum, rp, nnodes);
    k_copy_int<<<nb, 256, 0, stream>>>(rp, cursor, nnodes);
    k_scatter<<<(ne + 255) / 256, 256, 0, stream>>>(src, dst, emap, cursor, srcs, ais, dsts, ne);
}

extern "C" void kernel_launch(void* const* d_in, const int* in_sizes, int n_in,
                              void* d_out, int out_size, void* d_ws, size_t ws_size,
                              hipStream_t stream) {
    (void)in_sizes; (void)n_in;
    const float* x      = (const float*)d_in[0];
    const float* rw     = (const float*)d_in[1];
    const int*   eidx   = (const int*)d_in[3];
    const float* eattr  = (const float*)d_in[4];
    const float* ew     = (const float*)d_in[5];
    const float* ppe    = (const float*)d_in[6];
    const int*   nmap   = (const int*)d_in[7];
    const int*   csub   = (const int*)d_in[8];
    const int*   semap  = (const int*)d_in[9];
    const int*   sbatch = (const int*)d_in[10];
    const int*   cidx   = (const int*)d_in[11];
    const int*   tgts   = (const int*)d_in[12];
    const float* Win  = (const float*)d_in[14]; const float* bin  = (const float*)d_in[15];
    const float* Wrw  = (const float*)d_in[16]; const float* brw  = (const float*)d_in[17];
    const float* Wprw = (const float*)d_in[18]; const float* bprw = (const float*)d_in[19];
    const float* cWe  = (const float*)d_in[20]; const float* cbe  = (const float*)d_in[21];
    const float* cWl  = (const float*)d_in[22]; const float* cbl  = (const float*)d_in[23];
    const float* tWe  = (const float*)d_in[24]; const float* tbe  = (const float*)d_in[25];
    const float* tWl  = (const float*)d_in[26]; const float* tbl  = (const float*)d_in[27];
    const float* Wp1  = (const float*)d_in[28]; const float* bp1  = (const float*)d_in[29];
    const float* g1   = (const float*)d_in[30]; const float* be1  = (const float*)d_in[31];
    const float* Wp2  = (const float*)d_in[32]; const float* bp2  = (const float*)d_in[33];
    const float* g2   = (const float*)d_in[34]; const float* be2  = (const float*)d_in[35];
    const float* Wp3  = (const float*)d_in[36]; const float* bp3  = (const float*)d_in[37];
    float* out = (float*)d_out;

    // ---- workspace layout ----
    const size_t R = (size_t)cN * HH * sizeof(float);  // 102,400,000
    char* base = (char*)d_ws;
    float* R0f = (float*)base;
    float* R1f = (float*)(base + R);
    unsigned short* R0h = (unsigned short*)base;
    unsigned short* R1h = (unsigned short*)(base + R);
    int* ip = (int*)(base + 2 * R);
    int* rp_t  = ip;  ip += cN + 1;
    int* rp_c  = ip;  ip += cNS + 1;
    int* src_t = ip;  ip += cE;
    int* ai_t  = ip;  ip += cE;
    int* dst_t = ip;  ip += cE;
    int* src_c = ip;  ip += cES;
    int* ai_c  = ip;  ip += cES;
    int* dst_c = ip;  ip += cES;
    int* cursor = ip; ip += cNS;
    int* bsum  = ip;  ip += 2048;
    float* fp  = (float*)ip;
    float* mctx = fp; fp += (size_t)cNP * HH;
    float* mtgt = fp; fp += (size_t)cNP * HH;
    float* bufc = fp; fp += (size_t)2048 * HH;
    float* bufa = fp; fp += (size_t)2048 * HH;
    float* bufb = fp; fp += (size_t)2048 * HH;
    float* stats = fp; fp += 256;
    const size_t need = (size_t)((char*)fp - base);
    if (ws_size < need) {
        k_diag<<<(out_size + 255) / 256, 256, 0, stream>>>(out, out_size,
                                                           (float)(ws_size >> 20));
        return;
    }

    // ---- phase 0: build both CSRs ----
    build_csr(eidx, eidx + cE, nullptr, cN, cE, rp_t, src_t, ai_t, dst_t, cursor, bsum, stream);
    build_csr(csub, csub + cES, semap, cNS, cES, rp_c, src_c, ai_c, dst_c, cursor, bsum, stream);

    // ---- phase 1: target branch, f32 ping-pong R0 <-> R1 ----
    k_node_encode<<<cN, 128, 0, stream>>>(x, rw, Win, bin, Wrw, brw, R0f);
    {
        void* hp[2] = { (void*)R0f, (void*)R1f };
        for (int l = 0; l < cL; l++) {
            k_layer_fused<false><<<cN / 32, 256, 0, stream>>>(
                hp[l & 1], hp[(l & 1) ^ 1], rp_t, src_t, ai_t, dst_t, eattr, ew, tWe, tbe,
                tWl + (size_t)l * 2 * HH * HH, tbl + l * HH);
        }
    }
    k_seg_mean_f32<<<cNP, 128, 0, stream>>>(R0f, nmap, sbatch, mtgt, cNS);

    // ---- phase 2: context branch, bf16 ping-pong R0h <-> R1h ----
    k_encode_gather_bf16<<<cNS, 128, 0, stream>>>(x, rw, nmap, Win, bin, Wrw, brw, R0h);
    {
        void* hp[2] = { (void*)R0h, (void*)R1h };
        for (int l = 0; l < cL; l++) {
            k_layer_fused<true><<<cNS / 32, 256, 0, stream>>>(
                hp[l & 1], hp[(l & 1) ^ 1], rp_c, src_c, ai_c, dst_c, eattr, ew, cWe, cbe,
                cWl + (size_t)l * 2 * HH * HH, cbl + l * HH);
        }
    }
    k_seg_mean_bf16<<<cNP, 128, 0, stream>>>(R0h, sbatch, mctx, cNS);

    // ---- predictor head ----
    k_cond<<<cB * cPT, 128, 0, stream>>>(mctx, mtgt, cidx, tgts, ppe, Wprw, bprw, bufc, out);
    k_gemm_h<<<2048, 128, 0, stream>>>(bufc, Wp1, bp1, bufa);
    k_bn_stats<<<HH, 256, 0, stream>>>(bufa, stats, 2048);
    k_bn_relu<<<(2048 * HH) / 256, 256, 0, stream>>>(bufa, stats, g1, be1, 2048);
    k_gemm_h<<<2048, 128, 0, stream>>>(bufa, Wp2, bp2, bufb);
    k_bn_stats<<<HH, 256, 0, stream>>>(bufb, stats, 2048);
    k_bn_relu<<<(2048 * HH) / 256, 256, 0, stream>>>(bufb, stats, g2, be2, 2048);
    k_gemm_h<<<2048, 128, 0, stream>>>(bufb, Wp3, bp3, out + (size_t)2048 * HH);
}

// Round 7
// 8128.326 us; speedup vs baseline: 1.0761x; 1.0761x over previous
//
#include <hip/hip_runtime.h>

#define HH 128
constexpr int cN   = 200000;
constexpr int cE   = 800000;
constexpr int cNS  = 400000;
constexpr int cES  = 1600000;
constexpr int cB   = 512;
constexpr int cPPG = 8;
constexpr int cPT  = 4;
constexpr int cNP  = cB * cPPG;     // 4096 patches
constexpr int cNF  = 64;
constexpr int cNE  = 16;
constexpr int cRW  = 16;
constexpr int cPRW = 16;
constexpr int cL   = 4;

typedef __attribute__((ext_vector_type(8))) short s16x8;
typedef __attribute__((ext_vector_type(4))) float f32x4;

__device__ __forceinline__ float b2f(unsigned short b) {
    return __uint_as_float(((unsigned int)b) << 16);
}
__device__ __forceinline__ unsigned short f2b(float f) {
    unsigned int u = __float_as_uint(f);
    return (unsigned short)((u + 0x7fffu + ((u >> 16) & 1u)) >> 16);  // RNE
}

// ---------------- diagnostic ----------------
__global__ void k_diag(float* __restrict__ out, int n, float val) {
    int gid = blockIdx.x * 256 + threadIdx.x;
    if (gid < n) out[gid] = val;
}

__global__ void k_zero_int(int* __restrict__ p, int n) {
    int i = blockIdx.x * 256 + threadIdx.x;
    if (i < n) p[i] = 0;
}
__global__ void k_copy_int(const int* __restrict__ a, int* __restrict__ b, int n) {
    int i = blockIdx.x * 256 + threadIdx.x;
    if (i < n) b[i] = a[i];
}

// ---------------- CSR build ----------------
__global__ void k_hist(const int* __restrict__ dst, int* __restrict__ cnt, int ne) {
    int e = blockIdx.x * 256 + threadIdx.x;
    if (e < ne) atomicAdd(&cnt[dst[e]], 1);
}

__global__ void k_scan_local(const int* __restrict__ cnt, int* __restrict__ rp1,
                             int* __restrict__ bsum, int n) {
    __shared__ int s[256];
    int t = threadIdx.x;
    int i = blockIdx.x * 256 + t;
    s[t] = (i < n) ? cnt[i] : 0;
    __syncthreads();
    for (int off = 1; off < 256; off <<= 1) {
        int u = (t >= off) ? s[t - off] : 0;
        __syncthreads();
        s[t] += u;
        __syncthreads();
    }
    if (i < n) rp1[i] = s[t];
    if (t == 255) bsum[blockIdx.x] = s[255];
}

__global__ void k_scan_bsums(int* __restrict__ bsum, int nb) {
    __shared__ int s[256];
    __shared__ int carry;
    int t = threadIdx.x;
    if (t == 0) carry = 0;
    __syncthreads();
    for (int base = 0; base < nb; base += 256) {
        int i = base + t;
        s[t] = (i < nb) ? bsum[i] : 0;
        __syncthreads();
        for (int off = 1; off < 256; off <<= 1) {
            int u = (t >= off) ? s[t - off] : 0;
            __syncthreads();
            s[t] += u;
            __syncthreads();
        }
        int c = carry;
        if (i < nb) bsum[i] = s[t] + c;
        __syncthreads();
        if (t == 0) carry = c + s[255];
        __syncthreads();
    }
}

__global__ void k_rp_finalize(const int* __restrict__ bsum, int* __restrict__ rp, int n) {
    int i = blockIdx.x * 256 + threadIdx.x;
    if (i == 0) rp[0] = 0;
    if (i < n) {
        int blk = i >> 8;
        rp[i + 1] += blk ? bsum[blk - 1] : 0;
    }
}

__global__ void k_scatter(const int* __restrict__ src, const int* __restrict__ dst,
                          const int* __restrict__ emap, int* __restrict__ cursor,
                          int* __restrict__ srcs, int* __restrict__ ais,
                          int* __restrict__ dsts, int ne) {
    int e = blockIdx.x * 256 + threadIdx.x;
    if (e >= ne) return;
    int d = dst[e];
    int p = atomicAdd(&cursor[d], 1);
    srcs[p] = src[e];
    ais[p] = emap ? emap[e] : e;
    dsts[p] = d;
}

// ---------------- W -> bf16 MFMA-fragment layout, all 4 ctx layers ----------------
// Wfrag[l][ct][ks][lane][j] = bf16(W_l[ks*32 + (lane>>4)*8 + j][ct*16 + (lane&15)])
__global__ void k_wfrag(const float* __restrict__ Wl, unsigned short* __restrict__ Wfrag) {
    int g = blockIdx.x * 256 + threadIdx.x;   // 0..16383
    int l = g >> 12;
    int r = g & 4095;
    int ct = r >> 9, ks = (r >> 6) & 7, lane = r & 63;
    const float* W = Wl + (size_t)l * 2 * HH * HH;
    unsigned short o[8];
#pragma unroll
    for (int j = 0; j < 8; j++)
        o[j] = f2b(W[(size_t)(ks * 32 + (lane >> 4) * 8 + j) * HH + ct * 16 + (lane & 15)]);
#pragma unroll
    for (int j = 0; j < 8; j++) Wfrag[(size_t)g * 8 + j] = o[j];
}

// ---------------- node encoder: x0 = x@Win + bin + rw@Wrw + brw (f32 out) ----------------
__global__ void k_node_encode(const float* __restrict__ x, const float* __restrict__ rw,
                              const float* __restrict__ Win, const float* __restrict__ bin,
                              const float* __restrict__ Wrw, const float* __restrict__ brw,
                              float* __restrict__ x0) {
    __shared__ float sx[cNF];
    __shared__ float srw[cRW];
    int node = blockIdx.x;
    int t = threadIdx.x;  // 128
    if (t < cNF) sx[t] = x[(size_t)node * cNF + t];
    else if (t < cNF + cRW) srw[t - cNF] = rw[(size_t)node * cRW + (t - cNF)];
    __syncthreads();
    float acc = bin[t] + brw[t];
#pragma unroll
    for (int k = 0; k < cNF; k++) acc += sx[k] * Win[k * HH + t];
#pragma unroll
    for (int k = 0; k < cRW; k++) acc += srw[k] * Wrw[k * HH + t];
    x0[(size_t)node * HH + t] = acc;
}

// encoder fused with row gather, bf16 out
__global__ void k_encode_gather_bf16(const float* __restrict__ x, const float* __restrict__ rw,
                                     const int* __restrict__ map,
                                     const float* __restrict__ Win, const float* __restrict__ bin,
                                     const float* __restrict__ Wrw, const float* __restrict__ brw,
                                     unsigned short* __restrict__ out) {
    __shared__ float sx[cNF];
    __shared__ float srw[cRW];
    int node = map[blockIdx.x];
    int t = threadIdx.x;  // 128
    if (t < cNF) sx[t] = x[(size_t)node * cNF + t];
    else if (t < cNF + cRW) srw[t - cNF] = rw[(size_t)node * cRW + (t - cNF)];
    __syncthreads();
    float acc = bin[t] + brw[t];
#pragma unroll
    for (int k = 0; k < cNF; k++) acc += sx[k] * Win[k * HH + t];
#pragma unroll
    for (int k = 0; k < cRW; k++) acc += srw[k] * Wrw[k * HH + t];
    out[(size_t)blockIdx.x * HH + t] = f2b(acc);
}

// ---------------- ctx fused layer: wave-per-edge agg + bf16 MFMA GEMM ----------------
__global__ void __launch_bounds__(256)
k_layer_mfma(const unsigned short* __restrict__ h_in, unsigned short* __restrict__ h_out,
             const int* __restrict__ rp, const int* __restrict__ srcs,
             const int* __restrict__ ais, const int* __restrict__ dsts,
             const float* __restrict__ eattr, const float* __restrict__ ew,
             const float* __restrict__ We, const float* __restrict__ be,
             const unsigned short* __restrict__ Wfrag, const float* __restrict__ bias) {
    __shared__ unsigned short At[32][264];  // bf16 A-tile, +8 pad breaks read conflicts
    __shared__ float ag[32][HH];            // f32 agg accumulation
    int t = threadIdx.x;
    int base = blockIdx.x * 32;
    int lane = t & 63, w = t >> 6;

    // stage own h rows (bf16, 16B chunks): 32 rows x 16 chunks
    for (int i = t; i < 512; i += 256) {
        int r = i >> 4, cc = (i & 15) * 8;
        *(s16x8*)&At[r][cc] = *(const s16x8*)&h_in[(size_t)(base + r) * HH + cc];
    }
    for (int i = t; i < 32 * HH; i += 256) ((float*)ag)[i] = 0.f;
    __syncthreads();

    // wave-per-edge aggregation: lane covers channels 2*lane, 2*lane+1
    {
        int c0 = 2 * lane, c1 = c0 + 1;
        float we0[cNE], we1[cNE];
#pragma unroll
        for (int k = 0; k < cNE; k++) { we0[k] = We[k * HH + c0]; we1[k] = We[k * HH + c1]; }
        float be0 = be[c0], be1 = be[c1];
        int estart = rp[base], eend = rp[base + 32];
        for (int e = estart + w; e < eend; e += 4) {
            int s = srcs[e], ai = ais[e], d = dsts[e] - base;
            float wgt = ew[ai];
            const float* ea = eattr + (size_t)ai * cNE;
            float e0 = be0, e1 = be1;
#pragma unroll
            for (int k = 0; k < cNE; k++) { float av = ea[k]; e0 += av * we0[k]; e1 += av * we1[k]; }
            e0 = fmaxf(e0, 0.f); e1 = fmaxf(e1, 0.f);
            unsigned int hv = *(const unsigned int*)&h_in[(size_t)s * HH + c0];
            float h0 = b2f((unsigned short)hv), h1 = b2f((unsigned short)(hv >> 16));
            atomicAdd(&ag[d][c0], (h0 + e0) * wgt);
            atomicAdd(&ag[d][c1], (h1 + e1) * wgt);
        }
    }
    __syncthreads();
    // agg -> bf16 into A-tile second half
    for (int i = t; i < 32 * HH; i += 256) {
        int r = i >> 7, c = i & 127;
        At[r][HH + c] = f2b(ag[r][c]);
    }
    __syncthreads();

    // MFMA: wave w -> col-tiles 2w,2w+1; row-tiles 0,1; K=256 in 8 steps
    f32x4 acc[2][2];
#pragma unroll
    for (int i1 = 0; i1 < 2; i1++)
#pragma unroll
        for (int i2 = 0; i2 < 2; i2++) acc[i1][i2] = (f32x4)(0.f);
    int ar = lane & 15, g4 = lane >> 4;
#pragma unroll
    for (int ks = 0; ks < 8; ks++) {
        int ak = ks * 32 + g4 * 8;
        s16x8 a0 = *(const s16x8*)&At[ar][ak];
        s16x8 a1 = *(const s16x8*)&At[16 + ar][ak];
#pragma unroll
        for (int q = 0; q < 2; q++) {
            int ct = 2 * w + q;
            s16x8 bq = *(const s16x8*)&Wfrag[((size_t)(ct * 8 + ks) * 64 + lane) * 8];
            acc[0][q] = __builtin_amdgcn_mfma_f32_16x16x32_bf16(a0, bq, acc[0][q], 0, 0, 0);
            acc[1][q] = __builtin_amdgcn_mfma_f32_16x16x32_bf16(a1, bq, acc[1][q], 0, 0, 0);
        }
    }
    // C layout: col = ct*16 + (lane&15), row = rt*16 + (lane>>4)*4 + qi
#pragma unroll
    for (int rt = 0; rt < 2; rt++)
#pragma unroll
        for (int q = 0; q < 2; q++) {
            int col = (2 * w + q) * 16 + ar;
            float bv = bias[col];
#pragma unroll
            for (int qi = 0; qi < 4; qi++) {
                int row = base + rt * 16 + g4 * 4 + qi;
                h_out[(size_t)row * HH + col] = f2b(fmaxf(acc[rt][q][qi] + bv, 0.f));
            }
        }
}

// ---------------- target fused layer: wave-per-edge agg + f32 VALU GEMM ----------------
__global__ void __launch_bounds__(256)
k_layer_f32(const float* __restrict__ h_in, float* __restrict__ h_out,
            const int* __restrict__ rp, const int* __restrict__ srcs,
            const int* __restrict__ ais, const int* __restrict__ dsts,
            const float* __restrict__ eattr, const float* __restrict__ ew,
            const float* __restrict__ We, const float* __restrict__ be,
            const float* __restrict__ W, const float* __restrict__ b) {
    __shared__ float a[32][2 * HH];  // 32 KB
    int base = blockIdx.x * 32;
    int t = threadIdx.x;
    int lane = t & 63, w = t >> 6;

    for (int i = t; i < 32 * HH; i += 256) {
        int r = i >> 7, c = i & 127;
        a[r][c] = h_in[(size_t)(base + r) * HH + c];
        a[r][HH + c] = 0.f;
    }
    __syncthreads();

    // wave-per-edge aggregation
    {
        int c0 = 2 * lane, c1 = c0 + 1;
        float we0[cNE], we1[cNE];
#pragma unroll
        for (int k = 0; k < cNE; k++) { we0[k] = We[k * HH + c0]; we1[k] = We[k * HH + c1]; }
        float be0 = be[c0], be1 = be[c1];
        int estart = rp[base], eend = rp[base + 32];
        for (int e = estart + w; e < eend; e += 4) {
            int s = srcs[e], ai = ais[e], d = dsts[e] - base;
            float wgt = ew[ai];
            const float* ea = eattr + (size_t)ai * cNE;
            float e0 = be0, e1 = be1;
#pragma unroll
            for (int k = 0; k < cNE; k++) { float av = ea[k]; e0 += av * we0[k]; e1 += av * we1[k]; }
            e0 = fmaxf(e0, 0.f); e1 = fmaxf(e1, 0.f);
            float2 hv = *(const float2*)&h_in[(size_t)s * HH + c0];
            atomicAdd(&a[d][HH + c0], (hv.x + e0) * wgt);
            atomicAdd(&a[d][HH + c1], (hv.y + e1) * wgt);
        }
    }
    __syncthreads();

    // f32 GEMM: 32x128, 4x4 per thread
    int cg = t & 31;
    int rg = t >> 5;
    float acc[4][4];
#pragma unroll
    for (int r = 0; r < 4; r++)
#pragma unroll
        for (int c = 0; c < 4; c++) acc[r][c] = 0.f;
    for (int k = 0; k < 2 * HH; k += 4) {
        float4 av[4];
#pragma unroll
        for (int r = 0; r < 4; r++) av[r] = *(const float4*)&a[rg * 4 + r][k];
        float4 wv[4];
#pragma unroll
        for (int kk = 0; kk < 4; kk++) wv[kk] = *(const float4*)&W[(size_t)(k + kk) * HH + cg * 4];
#pragma unroll
        for (int r = 0; r < 4; r++) {
            float a0 = av[r].x, a1 = av[r].y, a2 = av[r].z, a3 = av[r].w;
            acc[r][0] += a0 * wv[0].x + a1 * wv[1].x + a2 * wv[2].x + a3 * wv[3].x;
            acc[r][1] += a0 * wv[0].y + a1 * wv[1].y + a2 * wv[2].y + a3 * wv[3].y;
            acc[r][2] += a0 * wv[0].z + a1 * wv[1].z + a2 * wv[2].z + a3 * wv[3].z;
            acc[r][3] += a0 * wv[0].w + a1 * wv[1].w + a2 * wv[2].w + a3 * wv[3].w;
        }
    }
    float4 bv = *(const float4*)&b[cg * 4];
#pragma unroll
    for (int r = 0; r < 4; r++) {
        int row = base + rg * 4 + r;
        float4 o;
        o.x = fmaxf(acc[r][0] + bv.x, 0.f);
        o.y = fmaxf(acc[r][1] + bv.y, 0.f);
        o.z = fmaxf(acc[r][2] + bv.z, 0.f);
        o.w = fmaxf(acc[r][3] + bv.w, 0.f);
        *(float4*)&h_out[(size_t)row * HH + cg * 4] = o;
    }
}

// ---------------- segmented mean over sorted batch ----------------
__global__ void k_seg_mean_f32(const float* __restrict__ src, const int* __restrict__ map,
                               const int* __restrict__ batch, float* __restrict__ out, int nrows) {
    int b = blockIdx.x;
    int t = threadIdx.x;  // 128
    int lo = 0, hi = nrows;
    while (lo < hi) { int m = (lo + hi) >> 1; if (batch[m] < b) lo = m + 1; else hi = m; }
    int s = lo;
    hi = nrows;
    while (lo < hi) { int m = (lo + hi) >> 1; if (batch[m] < b + 1) lo = m + 1; else hi = m; }
    int e = lo;
    float acc = 0.f;
    for (int r = s; r < e; r++) {
        size_t row = map ? (size_t)map[r] : (size_t)r;
        acc += src[row * HH + t];
    }
    out[(size_t)b * HH + t] = acc / fmaxf((float)(e - s), 1.f);
}

__global__ void k_seg_mean_bf16(const unsigned short* __restrict__ src,
                                const int* __restrict__ batch, float* __restrict__ out, int nrows) {
    int b = blockIdx.x;
    int t = threadIdx.x;  // 128
    int lo = 0, hi = nrows;
    while (lo < hi) { int m = (lo + hi) >> 1; if (batch[m] < b) lo = m + 1; else hi = m; }
    int s = lo;
    hi = nrows;
    while (lo < hi) { int m = (lo + hi) >> 1; if (batch[m] < b + 1) lo = m + 1; else hi = m; }
    int e = lo;
    float acc = 0.f;
    for (int r = s; r < e; r++) acc += b2f(src[(size_t)r * HH + t]);
    out[(size_t)b * HH + t] = acc / fmaxf((float)(e - s), 1.f);
}

// ---------------- head kernels ----------------
__global__ void k_cond(const float* __restrict__ mctx, const float* __restrict__ mtgt,
                       const int* __restrict__ cidx, const int* __restrict__ tgt_idxs,
                       const float* __restrict__ ppe, const float* __restrict__ Wprw,
                       const float* __restrict__ bprw, float* __restrict__ cond,
                       float* __restrict__ out0) {
    int r = blockIdx.x;   // 0..2047
    int t = threadIdx.x;  // 128
    int bg = r >> 2, tt = r & 3;
    int ti = tgt_idxs[bg * cPT + tt] + bg * cPPG;
    int ci = cidx[bg] + bg * cPPG;
    __shared__ float pe[cPRW];
    if (t < cPRW) pe[t] = ppe[(size_t)ti * cPRW + t];
    __syncthreads();
    float acc = bprw[t];
#pragma unroll
    for (int k = 0; k < cPRW; k++) acc += pe[k] * Wprw[k * HH + t];
    cond[(size_t)r * HH + t] = mctx[(size_t)ci * HH + t] + acc;
    out0[(size_t)r * HH + t] = mtgt[(size_t)ti * HH + t];
}

__global__ void k_gemm_h(const float* __restrict__ x, const float* __restrict__ W,
                         const float* __restrict__ b, float* __restrict__ y) {
    int r = blockIdx.x;
    int t = threadIdx.x;  // 128
    __shared__ float xr[HH];
    xr[t] = x[(size_t)r * HH + t];
    __syncthreads();
    float acc = b[t];
#pragma unroll 8
    for (int k = 0; k < HH; k++) acc += xr[k] * W[k * HH + t];
    y[(size_t)r * HH + t] = acc;
}

__global__ void k_bn_stats(const float* __restrict__ x, float* __restrict__ stats, int rows) {
    int c = blockIdx.x;
    int t = threadIdx.x;  // 256
    float s = 0.f, sq = 0.f;
    for (int r = t; r < rows; r += 256) {
        float v = x[(size_t)r * HH + c];
        s += v; sq += v * v;
    }
    __shared__ float bs[256], bq[256];
    bs[t] = s; bq[t] = sq;
    __syncthreads();
    for (int o = 128; o > 0; o >>= 1) {
        if (t < o) { bs[t] += bs[t + o]; bq[t] += bq[t + o]; }
        __syncthreads();
    }
    if (t == 0) {
        float m = bs[0] / rows;
        float var = bq[0] / rows - m * m;
        stats[c] = m;
        stats[HH + c] = rsqrtf(var + 1e-5f);
    }
}

__global__ void k_bn_relu(float* __restrict__ x, const float* __restrict__ stats,
                          const float* __restrict__ g, const float* __restrict__ be, int rows) {
    int gid = blockIdx.x * 256 + threadIdx.x;
    if (gid >= rows * HH) return;
    int c = gid & 127;
    float v = (x[gid] - stats[c]) * stats[HH + c] * g[c] + be[c];
    x[gid] = fmaxf(v, 0.f);
}

// ---------------- CSR build driver ----------------
static void build_csr(const int* src, const int* dst, const int* emap, int nnodes, int ne,
                      int* rp, int* srcs, int* ais, int* dsts, int* cursor, int* bsum,
                      hipStream_t stream) {
    int nb = (nnodes + 255) / 256;
    k_zero_int<<<nb, 256, 0, stream>>>(cursor, nnodes);
    k_hist<<<(ne + 255) / 256, 256, 0, stream>>>(dst, cursor, ne);
    k_scan_local<<<nb, 256, 0, stream>>>(cursor, rp + 1, bsum, nnodes);
    k_scan_bsums<<<1, 256, 0, stream>>>(bsum, nb);
    k_rp_finalize<<<nb, 256, 0, stream>>>(bsum, rp, nnodes);
    k_copy_int<<<nb, 256, 0, stream>>>(rp, cursor, nnodes);
    k_scatter<<<(ne + 255) / 256, 256, 0, stream>>>(src, dst, emap, cursor, srcs, ais, dsts, ne);
}

extern "C" void kernel_launch(void* const* d_in, const int* in_sizes, int n_in,
                              void* d_out, int out_size, void* d_ws, size_t ws_size,
                              hipStream_t stream) {
    (void)in_sizes; (void)n_in;
    const float* x      = (const float*)d_in[0];
    const float* rw     = (const float*)d_in[1];
    const int*   eidx   = (const int*)d_in[3];
    const float* eattr  = (const float*)d_in[4];
    const float* ew     = (const float*)d_in[5];
    const float* ppe    = (const float*)d_in[6];
    const int*   nmap   = (const int*)d_in[7];
    const int*   csub   = (const int*)d_in[8];
    const int*   semap  = (const int*)d_in[9];
    const int*   sbatch = (const int*)d_in[10];
    const int*   cidx   = (const int*)d_in[11];
    const int*   tgts   = (const int*)d_in[12];
    const float* Win  = (const float*)d_in[14]; const float* bin  = (const float*)d_in[15];
    const float* Wrw  = (const float*)d_in[16]; const float* brw  = (const float*)d_in[17];
    const float* Wprw = (const float*)d_in[18]; const float* bprw = (const float*)d_in[19];
    const float* cWe  = (const float*)d_in[20]; const float* cbe  = (const float*)d_in[21];
    const float* cWl  = (const float*)d_in[22]; const float* cbl  = (const float*)d_in[23];
    const float* tWe  = (const float*)d_in[24]; const float* tbe  = (const float*)d_in[25];
    const float* tWl  = (const float*)d_in[26]; const float* tbl  = (const float*)d_in[27];
    const float* Wp1  = (const float*)d_in[28]; const float* bp1  = (const float*)d_in[29];
    const float* g1   = (const float*)d_in[30]; const float* be1  = (const float*)d_in[31];
    const float* Wp2  = (const float*)d_in[32]; const float* bp2  = (const float*)d_in[33];
    const float* g2   = (const float*)d_in[34]; const float* be2  = (const float*)d_in[35];
    const float* Wp3  = (const float*)d_in[36]; const float* bp3  = (const float*)d_in[37];
    float* out = (float*)d_out;

    // ---- workspace layout ----
    const size_t R = (size_t)cN * HH * sizeof(float);  // 102,400,000
    char* base = (char*)d_ws;
    float* R0f = (float*)base;
    float* R1f = (float*)(base + R);
    unsigned short* R0h = (unsigned short*)base;
    unsigned short* R1h = (unsigned short*)(base + R);
    int* ip = (int*)(base + 2 * R);
    int* rp_t  = ip;  ip += cN + 1;
    int* rp_c  = ip;  ip += cNS + 1;
    int* src_t = ip;  ip += cE;
    int* ai_t  = ip;  ip += cE;
    int* dst_t = ip;  ip += cE;
    int* src_c = ip;  ip += cES;
    int* ai_c  = ip;  ip += cES;
    int* dst_c = ip;  ip += cES;
    int* cursor = ip; ip += cNS;
    int* bsum  = ip;  ip += 2048;
    // align to 16B for vectorized Wfrag / float buffers
    char* cp = (char*)(((uintptr_t)ip + 15) & ~(uintptr_t)15);
    unsigned short* wfrag = (unsigned short*)cp;     // 4 layers x 32768 bf16
    cp += (size_t)cL * 4096 * 8 * sizeof(unsigned short);
    float* fp  = (float*)cp;
    float* mctx = fp; fp += (size_t)cNP * HH;
    float* mtgt = fp; fp += (size_t)cNP * HH;
    float* bufc = fp; fp += (size_t)2048 * HH;
    float* bufa = fp; fp += (size_t)2048 * HH;
    float* bufb = fp; fp += (size_t)2048 * HH;
    float* stats = fp; fp += 256;
    const size_t need = (size_t)((char*)fp - base);
    if (ws_size < need) {
        k_diag<<<(out_size + 255) / 256, 256, 0, stream>>>(out, out_size,
                                                           (float)(ws_size >> 20));
        return;
    }

    // ---- phase 0: CSRs + ctx W fragments ----
    build_csr(eidx, eidx + cE, nullptr, cN, cE, rp_t, src_t, ai_t, dst_t, cursor, bsum, stream);
    build_csr(csub, csub + cES, semap, cNS, cES, rp_c, src_c, ai_c, dst_c, cursor, bsum, stream);
    k_wfrag<<<64, 256, 0, stream>>>(cWl, wfrag);

    // ---- phase 1: target branch, f32 ping-pong R0 <-> R1 ----
    k_node_encode<<<cN, 128, 0, stream>>>(x, rw, Win, bin, Wrw, brw, R0f);
    {
        void* hp[2] = { (void*)R0f, (void*)R1f };
        for (int l = 0; l < cL; l++) {
            k_layer_f32<<<cN / 32, 256, 0, stream>>>(
                (const float*)hp[l & 1], (float*)hp[(l & 1) ^ 1], rp_t, src_t, ai_t, dst_t,
                eattr, ew, tWe, tbe, tWl + (size_t)l * 2 * HH * HH, tbl + l * HH);
        }
    }
    k_seg_mean_f32<<<cNP, 128, 0, stream>>>(R0f, nmap, sbatch, mtgt, cNS);

    // ---- phase 2: context branch, bf16 ping-pong + MFMA GEMM ----
    k_encode_gather_bf16<<<cNS, 128, 0, stream>>>(x, rw, nmap, Win, bin, Wrw, brw, R0h);
    {
        unsigned short* hp[2] = { R0h, R1h };
        for (int l = 0; l < cL; l++) {
            k_layer_mfma<<<cNS / 32, 256, 0, stream>>>(
                hp[l & 1], hp[(l & 1) ^ 1], rp_c, src_c, ai_c, dst_c,
                eattr, ew, cWe, cbe, wfrag + (size_t)l * 32768, cbl + l * HH);
        }
    }
    k_seg_mean_bf16<<<cNP, 128, 0, stream>>>(R0h, sbatch, mctx, cNS);

    // ---- predictor head ----
    k_cond<<<cB * cPT, 128, 0, stream>>>(mctx, mtgt, cidx, tgts, ppe, Wprw, bprw, bufc, out);
    k_gemm_h<<<2048, 128, 0, stream>>>(bufc, Wp1, bp1, bufa);
    k_bn_stats<<<HH, 256, 0, stream>>>(bufa, stats, 2048);
    k_bn_relu<<<(2048 * HH) / 256, 256, 0, stream>>>(bufa, stats, g1, be1, 2048);
    k_gemm_h<<<2048, 128, 0, stream>>>(bufa, Wp2, bp2, bufb);
    k_bn_stats<<<HH, 256, 0, stream>>>(bufb, stats, 2048);
    k_bn_relu<<<(2048 * HH) / 256, 256, 0, stream>>>(bufb, stats, g2, be2, 2048);
    k_gemm_h<<<2048, 128, 0, stream>>>(bufb, Wp3, bp3, out + (size_t)2048 * HH);
}

// Round 8
// 5283.147 us; speedup vs baseline: 1.6556x; 1.5385x over previous
//
#include <hip/hip_runtime.h>

#define HH 128
constexpr int cN   = 200000;
constexpr int cE   = 800000;
constexpr int cNS  = 400000;
constexpr int cES  = 1600000;
constexpr int cB   = 512;
constexpr int cPPG = 8;
constexpr int cPT  = 4;
constexpr int cNP  = cB * cPPG;     // 4096 patches
constexpr int cNF  = 64;
constexpr int cNE  = 16;
constexpr int cRW  = 16;
constexpr int cPRW = 16;
constexpr int cL   = 4;

typedef __attribute__((ext_vector_type(8))) short s16x8;
typedef __attribute__((ext_vector_type(4))) float f32x4;

__device__ __forceinline__ float b2f(unsigned short b) {
    return __uint_as_float(((unsigned int)b) << 16);
}
__device__ __forceinline__ unsigned short f2b(float f) {
    unsigned int u = __float_as_uint(f);
    return (unsigned short)((u + 0x7fffu + ((u >> 16) & 1u)) >> 16);  // RNE
}

// ---------------- diagnostic ----------------
__global__ void k_diag(float* __restrict__ out, int n, float val) {
    int gid = blockIdx.x * 256 + threadIdx.x;
    if (gid < n) out[gid] = val;
}

__global__ void k_zero_int(int* __restrict__ p, int n) {
    int i = blockIdx.x * 256 + threadIdx.x;
    if (i < n) p[i] = 0;
}
__global__ void k_copy_int(const int* __restrict__ a, int* __restrict__ b, int n) {
    int i = blockIdx.x * 256 + threadIdx.x;
    if (i < n) b[i] = a[i];
}

// ---------------- CSR build ----------------
__global__ void k_hist(const int* __restrict__ dst, int* __restrict__ cnt, int ne) {
    int e = blockIdx.x * 256 + threadIdx.x;
    if (e < ne) atomicAdd(&cnt[dst[e]], 1);
}

__global__ void k_scan_local(const int* __restrict__ cnt, int* __restrict__ rp1,
                             int* __restrict__ bsum, int n) {
    __shared__ int s[256];
    int t = threadIdx.x;
    int i = blockIdx.x * 256 + t;
    s[t] = (i < n) ? cnt[i] : 0;
    __syncthreads();
    for (int off = 1; off < 256; off <<= 1) {
        int u = (t >= off) ? s[t - off] : 0;
        __syncthreads();
        s[t] += u;
        __syncthreads();
    }
    if (i < n) rp1[i] = s[t];
    if (t == 255) bsum[blockIdx.x] = s[255];
}

__global__ void k_scan_bsums(int* __restrict__ bsum, int nb) {
    __shared__ int s[256];
    __shared__ int carry;
    int t = threadIdx.x;
    if (t == 0) carry = 0;
    __syncthreads();
    for (int base = 0; base < nb; base += 256) {
        int i = base + t;
        s[t] = (i < nb) ? bsum[i] : 0;
        __syncthreads();
        for (int off = 1; off < 256; off <<= 1) {
            int u = (t >= off) ? s[t - off] : 0;
            __syncthreads();
            s[t] += u;
            __syncthreads();
        }
        int c = carry;
        if (i < nb) bsum[i] = s[t] + c;
        __syncthreads();
        if (t == 0) carry = c + s[255];
        __syncthreads();
    }
}

__global__ void k_rp_finalize(const int* __restrict__ bsum, int* __restrict__ rp, int n) {
    int i = blockIdx.x * 256 + threadIdx.x;
    if (i == 0) rp[0] = 0;
    if (i < n) {
        int blk = i >> 8;
        rp[i + 1] += blk ? bsum[blk - 1] : 0;
    }
}

__global__ void k_scatter(const int* __restrict__ src, const int* __restrict__ dst,
                          const int* __restrict__ emap, int* __restrict__ cursor,
                          int* __restrict__ srcs, int* __restrict__ ais, int ne) {
    int e = blockIdx.x * 256 + threadIdx.x;
    if (e >= ne) return;
    int d = dst[e];
    int p = atomicAdd(&cursor[d], 1);
    srcs[p] = src[e];
    ais[p] = emap ? emap[e] : e;
}

// ---------------- W -> bf16 MFMA-fragment layout, all 4 ctx layers ----------------
__global__ void k_wfrag(const float* __restrict__ Wl, unsigned short* __restrict__ Wfrag) {
    int g = blockIdx.x * 256 + threadIdx.x;   // 0..16383
    int l = g >> 12;
    int r = g & 4095;
    int ct = r >> 9, ks = (r >> 6) & 7, lane = r & 63;
    const float* W = Wl + (size_t)l * 2 * HH * HH;
    unsigned short o[8];
#pragma unroll
    for (int j = 0; j < 8; j++)
        o[j] = f2b(W[(size_t)(ks * 32 + (lane >> 4) * 8 + j) * HH + ct * 16 + (lane & 15)]);
#pragma unroll
    for (int j = 0; j < 8; j++) Wfrag[(size_t)g * 8 + j] = o[j];
}

// ---------------- node encoder (f32 out) ----------------
__global__ void k_node_encode(const float* __restrict__ x, const float* __restrict__ rw,
                              const float* __restrict__ Win, const float* __restrict__ bin,
                              const float* __restrict__ Wrw, const float* __restrict__ brw,
                              float* __restrict__ x0) {
    __shared__ float sx[cNF];
    __shared__ float srw[cRW];
    int node = blockIdx.x;
    int t = threadIdx.x;  // 128
    if (t < cNF) sx[t] = x[(size_t)node * cNF + t];
    else if (t < cNF + cRW) srw[t - cNF] = rw[(size_t)node * cRW + (t - cNF)];
    __syncthreads();
    float acc = bin[t] + brw[t];
#pragma unroll
    for (int k = 0; k < cNF; k++) acc += sx[k] * Win[k * HH + t];
#pragma unroll
    for (int k = 0; k < cRW; k++) acc += srw[k] * Wrw[k * HH + t];
    x0[(size_t)node * HH + t] = acc;
}

// encoder fused with row gather, bf16 out
__global__ void k_encode_gather_bf16(const float* __restrict__ x, const float* __restrict__ rw,
                                     const int* __restrict__ map,
                                     const float* __restrict__ Win, const float* __restrict__ bin,
                                     const float* __restrict__ Wrw, const float* __restrict__ brw,
                                     unsigned short* __restrict__ out) {
    __shared__ float sx[cNF];
    __shared__ float srw[cRW];
    int node = map[blockIdx.x];
    int t = threadIdx.x;  // 128
    if (t < cNF) sx[t] = x[(size_t)node * cNF + t];
    else if (t < cNF + cRW) srw[t - cNF] = rw[(size_t)node * cRW + (t - cNF)];
    __syncthreads();
    float acc = bin[t] + brw[t];
#pragma unroll
    for (int k = 0; k < cNF; k++) acc += sx[k] * Win[k * HH + t];
#pragma unroll
    for (int k = 0; k < cRW; k++) acc += srw[k] * Wrw[k * HH + t];
    out[(size_t)blockIdx.x * HH + t] = f2b(acc);
}

// ---------------- ctx fused layer: 2-phase edge-parallel agg + bf16 MFMA GEMM ----------------
__global__ void __launch_bounds__(256)
k_layer_mfma(const unsigned short* __restrict__ h_in, unsigned short* __restrict__ h_out,
             const int* __restrict__ rp, const int* __restrict__ srcs,
             const int* __restrict__ ais,
             const float* __restrict__ eattr, const float* __restrict__ ew,
             const float* __restrict__ We, const float* __restrict__ be,
             const unsigned short* __restrict__ Wfrag, const float* __restrict__ bias) {
    __shared__ unsigned short At[32][264];   // A-tile: [0..127] h, [128..255] agg
    __shared__ unsigned short msg[64][132];  // chunk edge-MLP outputs (bf16)
    __shared__ float WeL[16][128];
    __shared__ float beL[128];
    __shared__ float wsl[64];
    int t = threadIdx.x;
    int base = blockIdx.x * 32;

    // stage We/be and own h rows
    for (int i = t; i < 16 * 128; i += 256) WeL[i >> 7][i & 127] = We[i];
    if (t < 128) beL[t] = be[t];
    for (int i = t; i < 512; i += 256) {
        int r = i >> 4, cc = (i & 15) * 8;
        *(s16x8*)&At[r][cc] = *(const s16x8*)&h_in[(size_t)(base + r) * HH + cc];
    }
    int eblk0 = rp[base], eblk1 = rp[base + 32];
    int prow = t >> 3, pch = (t & 7) * 16;           // phase-2 assignment
    int re0 = rp[base + prow], re1 = rp[base + prow + 1];
    float acc[16];
#pragma unroll
    for (int j = 0; j < 16; j++) acc[j] = 0.f;
    __syncthreads();

    for (int cs = eblk0; cs < eblk1; cs += 64) {
        int ce = min(cs + 64, eblk1);
        // phase 1: thread = (slot, quarter); 256 independent edge-MLP chains
        {
            int slot = t >> 2, q = t & 3;
            int e = cs + slot;
            if (e < ce) {
                int ai = ais[e];
                const float* ea = eattr + (size_t)ai * cNE;
                float eav[16];
#pragma unroll
                for (int k = 0; k < 16; k += 4) *(float4*)&eav[k] = *(const float4*)&ea[k];
                if (q == 0) wsl[slot] = ew[ai];
                int c0 = q * 32;
                float m[32];
#pragma unroll
                for (int c = 0; c < 32; c++) m[c] = beL[c0 + c];
#pragma unroll
                for (int k = 0; k < 16; k++) {
                    float ev = eav[k];
#pragma unroll
                    for (int c = 0; c < 32; c++) m[c] += ev * WeL[k][c0 + c];
                }
#pragma unroll
                for (int c = 0; c < 32; c++) msg[slot][c0 + c] = f2b(fmaxf(m[c], 0.f));
            }
        }
        __syncthreads();
        // phase 2: thread = (row, 16-ch slice); row's edges contiguous, f32 reg accum
        {
            int e0 = max(re0, cs), e1 = min(re1, ce);
            for (int e = e0; e < e1; e++) {
                int sl = e - cs;
                float w = wsl[sl];
                int s = srcs[e];
                const unsigned short* hrow = &h_in[(size_t)s * HH + pch];
#pragma unroll
                for (int j = 0; j < 16; j += 2) {
                    unsigned int hv = *(const unsigned int*)&hrow[j];
                    unsigned int mv = *(const unsigned int*)&msg[sl][pch + j];
                    acc[j]     += (b2f((unsigned short)hv) + b2f((unsigned short)mv)) * w;
                    acc[j + 1] += (b2f((unsigned short)(hv >> 16)) +
                                   b2f((unsigned short)(mv >> 16))) * w;
                }
            }
        }
        __syncthreads();
    }
    // agg -> A-tile second half
#pragma unroll
    for (int j = 0; j < 16; j++) At[prow][HH + pch + j] = f2b(acc[j]);
    __syncthreads();

    // MFMA: wave w -> col-tiles 2w,2w+1; row-tiles 0,1; K=256 in 8 steps
    int lane = t & 63, wv = t >> 6;
    f32x4 ac[2][2];
#pragma unroll
    for (int i1 = 0; i1 < 2; i1++)
#pragma unroll
        for (int i2 = 0; i2 < 2; i2++) ac[i1][i2] = (f32x4)(0.f);
    int ar = lane & 15, g4 = lane >> 4;
#pragma unroll
    for (int ks = 0; ks < 8; ks++) {
        int ak = ks * 32 + g4 * 8;
        s16x8 a0 = *(const s16x8*)&At[ar][ak];
        s16x8 a1 = *(const s16x8*)&At[16 + ar][ak];
#pragma unroll
        for (int q = 0; q < 2; q++) {
            int ct = 2 * wv + q;
            s16x8 bq = *(const s16x8*)&Wfrag[((size_t)(ct * 8 + ks) * 64 + lane) * 8];
            ac[0][q] = __builtin_amdgcn_mfma_f32_16x16x32_bf16(a0, bq, ac[0][q], 0, 0, 0);
            ac[1][q] = __builtin_amdgcn_mfma_f32_16x16x32_bf16(a1, bq, ac[1][q], 0, 0, 0);
        }
    }
#pragma unroll
    for (int rt = 0; rt < 2; rt++)
#pragma unroll
        for (int q = 0; q < 2; q++) {
            int col = (2 * wv + q) * 16 + ar;
            float bv = bias[col];
#pragma unroll
            for (int qi = 0; qi < 4; qi++) {
                int row = base + rt * 16 + g4 * 4 + qi;
                h_out[(size_t)row * HH + col] = f2b(fmaxf(ac[rt][q][qi] + bv, 0.f));
            }
        }
}

// ---------------- target fused layer: 2-phase edge-parallel agg + f32 VALU GEMM ----------------
__global__ void __launch_bounds__(256)
k_layer_f32(const float* __restrict__ h_in, float* __restrict__ h_out,
            const int* __restrict__ rp, const int* __restrict__ srcs,
            const int* __restrict__ ais,
            const float* __restrict__ eattr, const float* __restrict__ ew,
            const float* __restrict__ We, const float* __restrict__ be,
            const float* __restrict__ W, const float* __restrict__ b) {
    __shared__ float a[32][2 * HH];   // 32 KB
    __shared__ float msg[64][130];    // 33.3 KB (f32 msg)
    __shared__ float WeL[16][128];
    __shared__ float beL[128];
    __shared__ float wsl[64];
    int base = blockIdx.x * 32;
    int t = threadIdx.x;

    for (int i = t; i < 16 * 128; i += 256) WeL[i >> 7][i & 127] = We[i];
    if (t < 128) beL[t] = be[t];
    for (int i = t; i < 32 * HH; i += 256) {
        int r = i >> 7, c = i & 127;
        a[r][c] = h_in[(size_t)(base + r) * HH + c];
    }
    int eblk0 = rp[base], eblk1 = rp[base + 32];
    int prow = t >> 3, pch = (t & 7) * 16;
    int re0 = rp[base + prow], re1 = rp[base + prow + 1];
    float acc[16];
#pragma unroll
    for (int j = 0; j < 16; j++) acc[j] = 0.f;
    __syncthreads();

    for (int cs = eblk0; cs < eblk1; cs += 64) {
        int ce = min(cs + 64, eblk1);
        {
            int slot = t >> 2, q = t & 3;
            int e = cs + slot;
            if (e < ce) {
                int ai = ais[e];
                const float* ea = eattr + (size_t)ai * cNE;
                float eav[16];
#pragma unroll
                for (int k = 0; k < 16; k += 4) *(float4*)&eav[k] = *(const float4*)&ea[k];
                if (q == 0) wsl[slot] = ew[ai];
                int c0 = q * 32;
                float m[32];
#pragma unroll
                for (int c = 0; c < 32; c++) m[c] = beL[c0 + c];
#pragma unroll
                for (int k = 0; k < 16; k++) {
                    float ev = eav[k];
#pragma unroll
                    for (int c = 0; c < 32; c++) m[c] += ev * WeL[k][c0 + c];
                }
#pragma unroll
                for (int c = 0; c < 32; c++) msg[slot][c0 + c] = fmaxf(m[c], 0.f);
            }
        }
        __syncthreads();
        {
            int e0 = max(re0, cs), e1 = min(re1, ce);
            for (int e = e0; e < e1; e++) {
                int sl = e - cs;
                float w = wsl[sl];
                int s = srcs[e];
                const float* hrow = &h_in[(size_t)s * HH + pch];
#pragma unroll
                for (int j = 0; j < 16; j += 4) {
                    float4 hv = *(const float4*)&hrow[j];
                    acc[j]     += (hv.x + msg[sl][pch + j])     * w;
                    acc[j + 1] += (hv.y + msg[sl][pch + j + 1]) * w;
                    acc[j + 2] += (hv.z + msg[sl][pch + j + 2]) * w;
                    acc[j + 3] += (hv.w + msg[sl][pch + j + 3]) * w;
                }
            }
        }
        __syncthreads();
    }
#pragma unroll
    for (int j = 0; j < 16; j++) a[prow][HH + pch + j] = acc[j];
    __syncthreads();

    // f32 GEMM: 32x128, 4x4 per thread
    int cg = t & 31;
    int rg = t >> 5;
    float ac2[4][4];
#pragma unroll
    for (int r = 0; r < 4; r++)
#pragma unroll
        for (int c = 0; c < 4; c++) ac2[r][c] = 0.f;
    for (int k = 0; k < 2 * HH; k += 4) {
        float4 av[4];
#pragma unroll
        for (int r = 0; r < 4; r++) av[r] = *(const float4*)&a[rg * 4 + r][k];
        float4 wv[4];
#pragma unroll
        for (int kk = 0; kk < 4; kk++) wv[kk] = *(const float4*)&W[(size_t)(k + kk) * HH + cg * 4];
#pragma unroll
        for (int r = 0; r < 4; r++) {
            float a0 = av[r].x, a1 = av[r].y, a2 = av[r].z, a3 = av[r].w;
            ac2[r][0] += a0 * wv[0].x + a1 * wv[1].x + a2 * wv[2].x + a3 * wv[3].x;
            ac2[r][1] += a0 * wv[0].y + a1 * wv[1].y + a2 * wv[2].y + a3 * wv[3].y;
            ac2[r][2] += a0 * wv[0].z + a1 * wv[1].z + a2 * wv[2].z + a3 * wv[3].z;
            ac2[r][3] += a0 * wv[0].w + a1 * wv[1].w + a2 * wv[2].w + a3 * wv[3].w;
        }
    }
    float4 bv = *(const float4*)&b[cg * 4];
#pragma unroll
    for (int r = 0; r < 4; r++) {
        int row = base + rg * 4 + r;
        float4 o;
        o.x = fmaxf(ac2[r][0] + bv.x, 0.f);
        o.y = fmaxf(ac2[r][1] + bv.y, 0.f);
        o.z = fmaxf(ac2[r][2] + bv.z, 0.f);
        o.w = fmaxf(ac2[r][3] + bv.w, 0.f);
        *(float4*)&h_out[(size_t)row * HH + cg * 4] = o;
    }
}

// ---------------- segmented mean over sorted batch ----------------
__global__ void k_seg_mean_f32(const float* __restrict__ src, const int* __restrict__ map,
                               const int* __restrict__ batch, float* __restrict__ out, int nrows) {
    int b = blockIdx.x;
    int t = threadIdx.x;  // 128
    int lo = 0, hi = nrows;
    while (lo < hi) { int m = (lo + hi) >> 1; if (batch[m] < b) lo = m + 1; else hi = m; }
    int s = lo;
    hi = nrows;
    while (lo < hi) { int m = (lo + hi) >> 1; if (batch[m] < b + 1) lo = m + 1; else hi = m; }
    int e = lo;
    float acc = 0.f;
    for (int r = s; r < e; r++) {
        size_t row = map ? (size_t)map[r] : (size_t)r;
        acc += src[row * HH + t];
    }
    out[(size_t)b * HH + t] = acc / fmaxf((float)(e - s), 1.f);
}

__global__ void k_seg_mean_bf16(const unsigned short* __restrict__ src,
                                const int* __restrict__ batch, float* __restrict__ out, int nrows) {
    int b = blockIdx.x;
    int t = threadIdx.x;  // 128
    int lo = 0, hi = nrows;
    while (lo < hi) { int m = (lo + hi) >> 1; if (batch[m] < b) lo = m + 1; else hi = m; }
    int s = lo;
    hi = nrows;
    while (lo < hi) { int m = (lo + hi) >> 1; if (batch[m] < b + 1) lo = m + 1; else hi = m; }
    int e = lo;
    float acc = 0.f;
    for (int r = s; r < e; r++) acc += b2f(src[(size_t)r * HH + t]);
    out[(size_t)b * HH + t] = acc / fmaxf((float)(e - s), 1.f);
}

// ---------------- head kernels ----------------
__global__ void k_cond(const float* __restrict__ mctx, const float* __restrict__ mtgt,
                       const int* __restrict__ cidx, const int* __restrict__ tgt_idxs,
                       const float* __restrict__ ppe, const float* __restrict__ Wprw,
                       const float* __restrict__ bprw, float* __restrict__ cond,
                       float* __restrict__ out0) {
    int r = blockIdx.x;   // 0..2047
    int t = threadIdx.x;  // 128
    int bg = r >> 2, tt = r & 3;
    int ti = tgt_idxs[bg * cPT + tt] + bg * cPPG;
    int ci = cidx[bg] + bg * cPPG;
    __shared__ float pe[cPRW];
    if (t < cPRW) pe[t] = ppe[(size_t)ti * cPRW + t];
    __syncthreads();
    float acc = bprw[t];
#pragma unroll
    for (int k = 0; k < cPRW; k++) acc += pe[k] * Wprw[k * HH + t];
    cond[(size_t)r * HH + t] = mctx[(size_t)ci * HH + t] + acc;
    out0[(size_t)r * HH + t] = mtgt[(size_t)ti * HH + t];
}

__global__ void k_gemm_h(const float* __restrict__ x, const float* __restrict__ W,
                         const float* __restrict__ b, float* __restrict__ y) {
    int r = blockIdx.x;
    int t = threadIdx.x;  // 128
    __shared__ float xr[HH];
    xr[t] = x[(size_t)r * HH + t];
    __syncthreads();
    float acc = b[t];
#pragma unroll 8
    for (int k = 0; k < HH; k++) acc += xr[k] * W[k * HH + t];
    y[(size_t)r * HH + t] = acc;
}

__global__ void k_bn_stats(const float* __restrict__ x, float* __restrict__ stats, int rows) {
    int c = blockIdx.x;
    int t = threadIdx.x;  // 256
    float s = 0.f, sq = 0.f;
    for (int r = t; r < rows; r += 256) {
        float v = x[(size_t)r * HH + c];
        s += v; sq += v * v;
    }
    __shared__ float bs[256], bq[256];
    bs[t] = s; bq[t] = sq;
    __syncthreads();
    for (int o = 128; o > 0; o >>= 1) {
        if (t < o) { bs[t] += bs[t + o]; bq[t] += bq[t + o]; }
        __syncthreads();
    }
    if (t == 0) {
        float m = bs[0] / rows;
        float var = bq[0] / rows - m * m;
        stats[c] = m;
        stats[HH + c] = rsqrtf(var + 1e-5f);
    }
}

__global__ void k_bn_relu(float* __restrict__ x, const float* __restrict__ stats,
                          const float* __restrict__ g, const float* __restrict__ be, int rows) {
    int gid = blockIdx.x * 256 + threadIdx.x;
    if (gid >= rows * HH) return;
    int c = gid & 127;
    float v = (x[gid] - stats[c]) * stats[HH + c] * g[c] + be[c];
    x[gid] = fmaxf(v, 0.f);
}

// ---------------- CSR build driver ----------------
static void build_csr(const int* src, const int* dst, const int* emap, int nnodes, int ne,
                      int* rp, int* srcs, int* ais, int* cursor, int* bsum,
                      hipStream_t stream) {
    int nb = (nnodes + 255) / 256;
    k_zero_int<<<nb, 256, 0, stream>>>(cursor, nnodes);
    k_hist<<<(ne + 255) / 256, 256, 0, stream>>>(dst, cursor, ne);
    k_scan_local<<<nb, 256, 0, stream>>>(cursor, rp + 1, bsum, nnodes);
    k_scan_bsums<<<1, 256, 0, stream>>>(bsum, nb);
    k_rp_finalize<<<nb, 256, 0, stream>>>(bsum, rp, nnodes);
    k_copy_int<<<nb, 256, 0, stream>>>(rp, cursor, nnodes);
    k_scatter<<<(ne + 255) / 256, 256, 0, stream>>>(src, dst, emap, cursor, srcs, ais, ne);
}

extern "C" void kernel_launch(void* const* d_in, const int* in_sizes, int n_in,
                              void* d_out, int out_size, void* d_ws, size_t ws_size,
                              hipStream_t stream) {
    (void)in_sizes; (void)n_in;
    const float* x      = (const float*)d_in[0];
    const float* rw     = (const float*)d_in[1];
    const int*   eidx   = (const int*)d_in[3];
    const float* eattr  = (const float*)d_in[4];
    const float* ew     = (const float*)d_in[5];
    const float* ppe    = (const float*)d_in[6];
    const int*   nmap   = (const int*)d_in[7];
    const int*   csub   = (const int*)d_in[8];
    const int*   semap  = (const int*)d_in[9];
    const int*   sbatch = (const int*)d_in[10];
    const int*   cidx   = (const int*)d_in[11];
    const int*   tgts   = (const int*)d_in[12];
    const float* Win  = (const float*)d_in[14]; const float* bin  = (const float*)d_in[15];
    const float* Wrw  = (const float*)d_in[16]; const float* brw  = (const float*)d_in[17];
    const float* Wprw = (const float*)d_in[18]; const float* bprw = (const float*)d_in[19];
    const float* cWe  = (const float*)d_in[20]; const float* cbe  = (const float*)d_in[21];
    const float* cWl  = (const float*)d_in[22]; const float* cbl  = (const float*)d_in[23];
    const float* tWe  = (const float*)d_in[24]; const float* tbe  = (const float*)d_in[25];
    const float* tWl  = (const float*)d_in[26]; const float* tbl  = (const float*)d_in[27];
    const float* Wp1  = (const float*)d_in[28]; const float* bp1  = (const float*)d_in[29];
    const float* g1   = (const float*)d_in[30]; const float* be1  = (const float*)d_in[31];
    const float* Wp2  = (const float*)d_in[32]; const float* bp2  = (const float*)d_in[33];
    const float* g2   = (const float*)d_in[34]; const float* be2  = (const float*)d_in[35];
    const float* Wp3  = (const float*)d_in[36]; const float* bp3  = (const float*)d_in[37];
    float* out = (float*)d_out;

    // ---- workspace layout ----
    const size_t R = (size_t)cN * HH * sizeof(float);  // 102,400,000
    char* base = (char*)d_ws;
    float* R0f = (float*)base;
    float* R1f = (float*)(base + R);
    unsigned short* R0h = (unsigned short*)base;
    unsigned short* R1h = (unsigned short*)(base + R);
    int* ip = (int*)(base + 2 * R);
    int* rp_t  = ip;  ip += cN + 1;
    int* rp_c  = ip;  ip += cNS + 1;
    int* src_t = ip;  ip += cE;
    int* ai_t  = ip;  ip += cE;
    int* src_c = ip;  ip += cES;
    int* ai_c  = ip;  ip += cES;
    int* cursor = ip; ip += cNS;
    int* bsum  = ip;  ip += 2048;
    char* cp = (char*)(((uintptr_t)ip + 15) & ~(uintptr_t)15);
    unsigned short* wfrag = (unsigned short*)cp;     // 4 layers x 32768 bf16
    cp += (size_t)cL * 4096 * 8 * sizeof(unsigned short);
    float* fp  = (float*)cp;
    float* mctx = fp; fp += (size_t)cNP * HH;
    float* mtgt = fp; fp += (size_t)cNP * HH;
    float* bufc = fp; fp += (size_t)2048 * HH;
    float* bufa = fp; fp += (size_t)2048 * HH;
    float* bufb = fp; fp += (size_t)2048 * HH;
    float* stats = fp; fp += 256;
    const size_t need = (size_t)((char*)fp - base);
    if (ws_size < need) {
        k_diag<<<(out_size + 255) / 256, 256, 0, stream>>>(out, out_size,
                                                           (float)(ws_size >> 20));
        return;
    }

    // ---- phase 0: CSRs + ctx W fragments ----
    build_csr(eidx, eidx + cE, nullptr, cN, cE, rp_t, src_t, ai_t, cursor, bsum, stream);
    build_csr(csub, csub + cES, semap, cNS, cES, rp_c, src_c, ai_c, cursor, bsum, stream);
    k_wfrag<<<64, 256, 0, stream>>>(cWl, wfrag);

    // ---- phase 1: target branch, f32 ping-pong R0 <-> R1 ----
    k_node_encode<<<cN, 128, 0, stream>>>(x, rw, Win, bin, Wrw, brw, R0f);
    {
        void* hp[2] = { (void*)R0f, (void*)R1f };
        for (int l = 0; l < cL; l++) {
            k_layer_f32<<<cN / 32, 256, 0, stream>>>(
                (const float*)hp[l & 1], (float*)hp[(l & 1) ^ 1], rp_t, src_t, ai_t,
                eattr, ew, tWe, tbe, tWl + (size_t)l * 2 * HH * HH, tbl + l * HH);
        }
    }
    k_seg_mean_f32<<<cNP, 128, 0, stream>>>(R0f, nmap, sbatch, mtgt, cNS);

    // ---- phase 2: context branch, bf16 ping-pong + MFMA GEMM ----
    k_encode_gather_bf16<<<cNS, 128, 0, stream>>>(x, rw, nmap, Win, bin, Wrw, brw, R0h);
    {
        unsigned short* hp[2] = { R0h, R1h };
        for (int l = 0; l < cL; l++) {
            k_layer_mfma<<<cNS / 32, 256, 0, stream>>>(
                hp[l & 1], hp[(l & 1) ^ 1], rp_c, src_c, ai_c,
                eattr, ew, cWe, cbe, wfrag + (size_t)l * 32768, cbl + l * HH);
        }
    }
    k_seg_mean_bf16<<<cNP, 128, 0, stream>>>(R0h, sbatch, mctx, cNS);

    // ---- predictor head ----
    k_cond<<<cB * cPT, 128, 0, stream>>>(mctx, mtgt, cidx, tgts, ppe, Wprw, bprw, bufc, out);
    k_gemm_h<<<2048, 128, 0, stream>>>(bufc, Wp1, bp1, bufa);
    k_bn_stats<<<HH, 256, 0, stream>>>(bufa, stats, 2048);
    k_bn_relu<<<(2048 * HH) / 256, 256, 0, stream>>>(bufa, stats, g1, be1, 2048);
    k_gemm_h<<<2048, 128, 0, stream>>>(bufa, Wp2, bp2, bufb);
    k_bn_stats<<<HH, 256, 0, stream>>>(bufb, stats, 2048);
    k_bn_relu<<<(2048 * HH) / 256, 256, 0, stream>>>(bufb, stats, g2, be2, 2048);
    k_gemm_h<<<2048, 128, 0, stream>>>(bufb, Wp3, bp3, out + (size_t)2048 * HH);
}

// Round 9
// 4344.743 us; speedup vs baseline: 2.0132x; 1.2160x over previous
//
#include <hip/hip_runtime.h>

#define HH 128
constexpr int cN   = 200000;
constexpr int cE   = 800000;
constexpr int cNS  = 400000;
constexpr int cES  = 1600000;
constexpr int cB   = 512;
constexpr int cPPG = 8;
constexpr int cPT  = 4;
constexpr int cNP  = cB * cPPG;     // 4096 patches
constexpr int cNF  = 64;
constexpr int cNE  = 16;
constexpr int cRW  = 16;
constexpr int cPRW = 16;
constexpr int cL   = 4;

typedef __attribute__((ext_vector_type(8))) short s16x8;
typedef __attribute__((ext_vector_type(4))) float f32x4;

__device__ __forceinline__ float b2f(unsigned short b) {
    return __uint_as_float(((unsigned int)b) << 16);
}
__device__ __forceinline__ unsigned short f2b(float f) {
    unsigned int u = __float_as_uint(f);
    return (unsigned short)((u + 0x7fffu + ((u >> 16) & 1u)) >> 16);  // RNE
}

// ---------------- diagnostic ----------------
__global__ void k_diag(float* __restrict__ out, int n, float val) {
    int gid = blockIdx.x * 256 + threadIdx.x;
    if (gid < n) out[gid] = val;
}

__global__ void k_zero_int(int* __restrict__ p, int n) {
    int i = blockIdx.x * 256 + threadIdx.x;
    if (i < n) p[i] = 0;
}
__global__ void k_copy_int(const int* __restrict__ a, int* __restrict__ b, int n) {
    int i = blockIdx.x * 256 + threadIdx.x;
    if (i < n) b[i] = a[i];
}

// ---------------- CSR build ----------------
__global__ void k_hist(const int* __restrict__ dst, int* __restrict__ cnt, int ne) {
    int e = blockIdx.x * 256 + threadIdx.x;
    if (e < ne) atomicAdd(&cnt[dst[e]], 1);
}

__global__ void k_scan_local(const int* __restrict__ cnt, int* __restrict__ rp1,
                             int* __restrict__ bsum, int n) {
    __shared__ int s[256];
    int t = threadIdx.x;
    int i = blockIdx.x * 256 + t;
    s[t] = (i < n) ? cnt[i] : 0;
    __syncthreads();
    for (int off = 1; off < 256; off <<= 1) {
        int u = (t >= off) ? s[t - off] : 0;
        __syncthreads();
        s[t] += u;
        __syncthreads();
    }
    if (i < n) rp1[i] = s[t];
    if (t == 255) bsum[blockIdx.x] = s[255];
}

__global__ void k_scan_bsums(int* __restrict__ bsum, int nb) {
    __shared__ int s[256];
    __shared__ int carry;
    int t = threadIdx.x;
    if (t == 0) carry = 0;
    __syncthreads();
    for (int base = 0; base < nb; base += 256) {
        int i = base + t;
        s[t] = (i < nb) ? bsum[i] : 0;
        __syncthreads();
        for (int off = 1; off < 256; off <<= 1) {
            int u = (t >= off) ? s[t - off] : 0;
            __syncthreads();
            s[t] += u;
            __syncthreads();
        }
        int c = carry;
        if (i < nb) bsum[i] = s[t] + c;
        __syncthreads();
        if (t == 0) carry = c + s[255];
        __syncthreads();
    }
}

__global__ void k_rp_finalize(const int* __restrict__ bsum, int* __restrict__ rp, int n) {
    int i = blockIdx.x * 256 + threadIdx.x;
    if (i == 0) rp[0] = 0;
    if (i < n) {
        int blk = i >> 8;
        rp[i + 1] += blk ? bsum[blk - 1] : 0;
    }
}

__global__ void k_scatter(const int* __restrict__ src, const int* __restrict__ dst,
                          const int* __restrict__ emap, int* __restrict__ cursor,
                          int* __restrict__ srcs, int* __restrict__ ais, int ne) {
    int e = blockIdx.x * 256 + threadIdx.x;
    if (e >= ne) return;
    int d = dst[e];
    int p = atomicAdd(&cursor[d], 1);
    srcs[p] = src[e];
    ais[p] = emap ? emap[e] : e;
}

// ---------------- W -> bf16 MFMA fragments: 4 ctx (hi), 4 tgt hi, 4 tgt lo ----------------
__global__ void k_wfrag_all(const float* __restrict__ cWl, const float* __restrict__ tWl,
                            unsigned short* __restrict__ fC, unsigned short* __restrict__ fTH,
                            unsigned short* __restrict__ fTL) {
    int g = blockIdx.x * 256 + threadIdx.x;   // 12 * 4096
    int set = g >> 12;
    int r = g & 4095;
    int ct = r >> 9, ks = (r >> 6) & 7, lane = r & 63;
    const float* W;
    unsigned short* outp;
    bool lo = false;
    if (set < 4)      { W = cWl + (size_t)set * 2 * HH * HH;       outp = fC  + (size_t)set * 32768; }
    else if (set < 8) { W = tWl + (size_t)(set - 4) * 2 * HH * HH; outp = fTH + (size_t)(set - 4) * 32768; }
    else              { W = tWl + (size_t)(set - 8) * 2 * HH * HH; outp = fTL + (size_t)(set - 8) * 32768; lo = true; }
#pragma unroll
    for (int j = 0; j < 8; j++) {
        float w = W[(size_t)(ks * 32 + (lane >> 4) * 8 + j) * HH + ct * 16 + (lane & 15)];
        unsigned short hi = f2b(w);
        outp[(size_t)r * 8 + j] = lo ? f2b(w - b2f(hi)) : hi;
    }
}

// ---------------- node encoder (f32 out) ----------------
__global__ void k_node_encode(const float* __restrict__ x, const float* __restrict__ rw,
                              const float* __restrict__ Win, const float* __restrict__ bin,
                              const float* __restrict__ Wrw, const float* __restrict__ brw,
                              float* __restrict__ x0) {
    __shared__ float sx[cNF];
    __shared__ float srw[cRW];
    int node = blockIdx.x;
    int t = threadIdx.x;  // 128
    if (t < cNF) sx[t] = x[(size_t)node * cNF + t];
    else if (t < cNF + cRW) srw[t - cNF] = rw[(size_t)node * cRW + (t - cNF)];
    __syncthreads();
    float acc = bin[t] + brw[t];
#pragma unroll
    for (int k = 0; k < cNF; k++) acc += sx[k] * Win[k * HH + t];
#pragma unroll
    for (int k = 0; k < cRW; k++) acc += srw[k] * Wrw[k * HH + t];
    x0[(size_t)node * HH + t] = acc;
}

// encoder fused with row gather, bf16 out
__global__ void k_encode_gather_bf16(const float* __restrict__ x, const float* __restrict__ rw,
                                     const int* __restrict__ map,
                                     const float* __restrict__ Win, const float* __restrict__ bin,
                                     const float* __restrict__ Wrw, const float* __restrict__ brw,
                                     unsigned short* __restrict__ out) {
    __shared__ float sx[cNF];
    __shared__ float srw[cRW];
    int node = map[blockIdx.x];
    int t = threadIdx.x;  // 128
    if (t < cNF) sx[t] = x[(size_t)node * cNF + t];
    else if (t < cNF + cRW) srw[t - cNF] = rw[(size_t)node * cRW + (t - cNF)];
    __syncthreads();
    float acc = bin[t] + brw[t];
#pragma unroll
    for (int k = 0; k < cNF; k++) acc += sx[k] * Win[k * HH + t];
#pragma unroll
    for (int k = 0; k < cRW; k++) acc += srw[k] * Wrw[k * HH + t];
    out[(size_t)blockIdx.x * HH + t] = f2b(acc);
}

// ---------------- ctx layer: edge-parallel agg + bf16 MFMA; LDS union, 26 KB ----------------
__global__ void __launch_bounds__(256)
k_layer_ctx(const unsigned short* __restrict__ h_in, unsigned short* __restrict__ h_out,
            const int* __restrict__ rp, const int* __restrict__ srcs,
            const int* __restrict__ ais,
            const float* __restrict__ eattr, const float* __restrict__ ew,
            const float* __restrict__ We, const float* __restrict__ be,
            const unsigned short* __restrict__ Wfrag, const float* __restrict__ bias) {
    __shared__ unsigned short pool[8448];   // union: msg[64][130] (16640B) | At[32][264] (16896B)
    __shared__ float WeL[16][128];
    __shared__ float beL[128];
    __shared__ float wsl[64];
    auto msg = (unsigned short (*)[130])pool;
    auto At  = (unsigned short (*)[264])pool;
    int t = threadIdx.x;
    int base = blockIdx.x * 32;

    for (int i = t; i < 2048; i += 256) WeL[i >> 7][i & 127] = We[i];
    if (t < 128) beL[t] = be[t];
    int eblk0 = rp[base], eblk1 = rp[base + 32];
    int prow = t >> 3, pch = (t & 7) * 16;
    int re0 = rp[base + prow], re1 = rp[base + prow + 1];
    float acc[16];
#pragma unroll
    for (int j = 0; j < 16; j++) acc[j] = 0.f;
    __syncthreads();

    for (int cs = eblk0; cs < eblk1; cs += 64) {
        int ce = min(cs + 64, eblk1);
        // phase 1: slot = t&63 (64 lanes = 64 distinct slots -> 2-way banks), q = t>>6
        {
            int slot = t & 63, q = t >> 6;
            int e = cs + slot;
            if (e < ce) {
                int ai = ais[e];
                if (q == 0) wsl[slot] = ew[ai];
                const float* ea = eattr + (size_t)ai * cNE;
                float eav[16];
#pragma unroll
                for (int k = 0; k < 16; k += 4) *(float4*)&eav[k] = *(const float4*)&ea[k];
                int c0 = q * 32;
                float m[32];
#pragma unroll
                for (int c = 0; c < 32; c++) m[c] = beL[c0 + c];
#pragma unroll
                for (int k = 0; k < 16; k++) {
                    float ev = eav[k];
#pragma unroll
                    for (int c = 0; c < 32; c++) m[c] += ev * WeL[k][c0 + c];
                }
#pragma unroll
                for (int c = 0; c < 32; c++) msg[slot][c0 + c] = f2b(fmaxf(m[c], 0.f));
            }
        }
        __syncthreads();
        // phase 2: thread = (row, 16-ch slice), f32 register accum
        {
            int e0 = max(re0, cs), e1 = min(re1, ce);
            for (int e = e0; e < e1; e++) {
                int sl = e - cs;
                float w = wsl[sl];
                int s = srcs[e];
                const unsigned short* hrow = &h_in[(size_t)s * HH + pch];
#pragma unroll
                for (int j = 0; j < 16; j += 2) {
                    unsigned int hv = *(const unsigned int*)&hrow[j];
                    unsigned int mv = *(const unsigned int*)&msg[sl][pch + j];
                    acc[j]     += (b2f((unsigned short)hv) + b2f((unsigned short)mv)) * w;
                    acc[j + 1] += (b2f((unsigned short)(hv >> 16)) +
                                   b2f((unsigned short)(mv >> 16))) * w;
                }
            }
        }
        __syncthreads();
    }
    // build A-tile (msg is dead): agg half from registers, own-h half from global
#pragma unroll
    for (int j = 0; j < 16; j++) At[prow][HH + pch + j] = f2b(acc[j]);
    for (int i = t; i < 512; i += 256) {
        int r = i >> 4, cc = (i & 15) * 8;
        *(s16x8*)&At[r][cc] = *(const s16x8*)&h_in[(size_t)(base + r) * HH + cc];
    }
    __syncthreads();

    // MFMA: wave wv -> col-tiles 2wv,2wv+1; row-tiles 0,1; K=256 in 8 steps
    int lane = t & 63, wv = t >> 6;
    f32x4 ac[2][2];
#pragma unroll
    for (int i1 = 0; i1 < 2; i1++)
#pragma unroll
        for (int i2 = 0; i2 < 2; i2++) ac[i1][i2] = (f32x4)(0.f);
    int ar = lane & 15, g4 = lane >> 4;
#pragma unroll
    for (int ks = 0; ks < 8; ks++) {
        int ak = ks * 32 + g4 * 8;
        s16x8 a0 = *(const s16x8*)&At[ar][ak];
        s16x8 a1 = *(const s16x8*)&At[16 + ar][ak];
#pragma unroll
        for (int q = 0; q < 2; q++) {
            int ct = 2 * wv + q;
            s16x8 bq = *(const s16x8*)&Wfrag[((size_t)(ct * 8 + ks) * 64 + lane) * 8];
            ac[0][q] = __builtin_amdgcn_mfma_f32_16x16x32_bf16(a0, bq, ac[0][q], 0, 0, 0);
            ac[1][q] = __builtin_amdgcn_mfma_f32_16x16x32_bf16(a1, bq, ac[1][q], 0, 0, 0);
        }
    }
#pragma unroll
    for (int rt = 0; rt < 2; rt++)
#pragma unroll
        for (int q = 0; q < 2; q++) {
            int col = (2 * wv + q) * 16 + ar;
            float bv = bias[col];
#pragma unroll
            for (int qi = 0; qi < 4; qi++) {
                int row = base + rt * 16 + g4 * 4 + qi;
                h_out[(size_t)row * HH + col] = f2b(fmaxf(ac[rt][q][qi] + bv, 0.f));
            }
        }
}

// ---------------- tgt layer: edge-parallel agg + bf16x3 MFMA GEMM (f32-accurate) ----------------
__global__ void __launch_bounds__(256)
k_layer_tgt(const float* __restrict__ h_in, float* __restrict__ h_out,
            const int* __restrict__ rp, const int* __restrict__ srcs,
            const int* __restrict__ ais,
            const float* __restrict__ eattr, const float* __restrict__ ew,
            const float* __restrict__ We, const float* __restrict__ be,
            const unsigned short* __restrict__ WfH, const unsigned short* __restrict__ WfL,
            const float* __restrict__ bias) {
    __shared__ unsigned short pool[16896];  // union: msg f32[64][129] (33024B) | At_hi+At_lo (33792B)
    __shared__ float WeL[16][128];
    __shared__ float beL[128];
    __shared__ float wsl[64];
    auto msg  = (float (*)[129])pool;
    auto AtH  = (unsigned short (*)[264])pool;
    auto AtL  = (unsigned short (*)[264])(pool + 8448);
    int t = threadIdx.x;
    int base = blockIdx.x * 32;

    for (int i = t; i < 2048; i += 256) WeL[i >> 7][i & 127] = We[i];
    if (t < 128) beL[t] = be[t];
    int eblk0 = rp[base], eblk1 = rp[base + 32];
    int prow = t >> 3, pch = (t & 7) * 16;
    int re0 = rp[base + prow], re1 = rp[base + prow + 1];
    float acc[16];
#pragma unroll
    for (int j = 0; j < 16; j++) acc[j] = 0.f;
    __syncthreads();

    for (int cs = eblk0; cs < eblk1; cs += 64) {
        int ce = min(cs + 64, eblk1);
        {
            int slot = t & 63, q = t >> 6;
            int e = cs + slot;
            if (e < ce) {
                int ai = ais[e];
                if (q == 0) wsl[slot] = ew[ai];
                const float* ea = eattr + (size_t)ai * cNE;
                float eav[16];
#pragma unroll
                for (int k = 0; k < 16; k += 4) *(float4*)&eav[k] = *(const float4*)&ea[k];
                int c0 = q * 32;
                float m[32];
#pragma unroll
                for (int c = 0; c < 32; c++) m[c] = beL[c0 + c];
#pragma unroll
                for (int k = 0; k < 16; k++) {
                    float ev = eav[k];
#pragma unroll
                    for (int c = 0; c < 32; c++) m[c] += ev * WeL[k][c0 + c];
                }
#pragma unroll
                for (int c = 0; c < 32; c++) msg[slot][c0 + c] = fmaxf(m[c], 0.f);
            }
        }
        __syncthreads();
        {
            int e0 = max(re0, cs), e1 = min(re1, ce);
            for (int e = e0; e < e1; e++) {
                int sl = e - cs;
                float w = wsl[sl];
                int s = srcs[e];
                const float* hrow = &h_in[(size_t)s * HH + pch];
#pragma unroll
                for (int j = 0; j < 16; j += 4) {
                    float4 hv = *(const float4*)&hrow[j];
                    acc[j]     += (hv.x + msg[sl][pch + j])     * w;
                    acc[j + 1] += (hv.y + msg[sl][pch + j + 1]) * w;
                    acc[j + 2] += (hv.z + msg[sl][pch + j + 2]) * w;
                    acc[j + 3] += (hv.w + msg[sl][pch + j + 3]) * w;
                }
            }
        }
        __syncthreads();
    }
    // build hi/lo split A-tile (msg dead)
#pragma unroll
    for (int j = 0; j < 16; j++) {
        float v = acc[j];
        unsigned short hi = f2b(v);
        AtH[prow][HH + pch + j] = hi;
        AtL[prow][HH + pch + j] = f2b(v - b2f(hi));
    }
    for (int i = t; i < 32 * HH; i += 256) {
        int r = i >> 7, c = i & 127;
        float v = h_in[(size_t)(base + r) * HH + c];
        unsigned short hi = f2b(v);
        AtH[r][c] = hi;
        AtL[r][c] = f2b(v - b2f(hi));
    }
    __syncthreads();

    // bf16x3 MFMA: acc = aH*bH + aL*bH + aH*bL  (error ~2^-16 relative)
    int lane = t & 63, wv = t >> 6;
    f32x4 ac[2][2];
#pragma unroll
    for (int i1 = 0; i1 < 2; i1++)
#pragma unroll
        for (int i2 = 0; i2 < 2; i2++) ac[i1][i2] = (f32x4)(0.f);
    int ar = lane & 15, g4 = lane >> 4;
#pragma unroll
    for (int ks = 0; ks < 8; ks++) {
        int ak = ks * 32 + g4 * 8;
        s16x8 a0h = *(const s16x8*)&AtH[ar][ak];
        s16x8 a1h = *(const s16x8*)&AtH[16 + ar][ak];
        s16x8 a0l = *(const s16x8*)&AtL[ar][ak];
        s16x8 a1l = *(const s16x8*)&AtL[16 + ar][ak];
#pragma unroll
        for (int q = 0; q < 2; q++) {
            int ct = 2 * wv + q;
            size_t fo = ((size_t)(ct * 8 + ks) * 64 + lane) * 8;
            s16x8 bh = *(const s16x8*)&WfH[fo];
            s16x8 bl = *(const s16x8*)&WfL[fo];
            ac[0][q] = __builtin_amdgcn_mfma_f32_16x16x32_bf16(a0h, bh, ac[0][q], 0, 0, 0);
            ac[0][q] = __builtin_amdgcn_mfma_f32_16x16x32_bf16(a0l, bh, ac[0][q], 0, 0, 0);
            ac[0][q] = __builtin_amdgcn_mfma_f32_16x16x32_bf16(a0h, bl, ac[0][q], 0, 0, 0);
            ac[1][q] = __builtin_amdgcn_mfma_f32_16x16x32_bf16(a1h, bh, ac[1][q], 0, 0, 0);
            ac[1][q] = __builtin_amdgcn_mfma_f32_16x16x32_bf16(a1l, bh, ac[1][q], 0, 0, 0);
            ac[1][q] = __builtin_amdgcn_mfma_f32_16x16x32_bf16(a1h, bl, ac[1][q], 0, 0, 0);
        }
    }
#pragma unroll
    for (int rt = 0; rt < 2; rt++)
#pragma unroll
        for (int q = 0; q < 2; q++) {
            int col = (2 * wv + q) * 16 + ar;
            float bv = bias[col];
#pragma unroll
            for (int qi = 0; qi < 4; qi++) {
                int row = base + rt * 16 + g4 * 4 + qi;
                h_out[(size_t)row * HH + col] = fmaxf(ac[rt][q][qi] + bv, 0.f);
            }
        }
}

// ---------------- segmented mean over sorted batch ----------------
__global__ void k_seg_mean_f32(const float* __restrict__ src, const int* __restrict__ map,
                               const int* __restrict__ batch, float* __restrict__ out, int nrows) {
    int b = blockIdx.x;
    int t = threadIdx.x;  // 128
    int lo = 0, hi = nrows;
    while (lo < hi) { int m = (lo + hi) >> 1; if (batch[m] < b) lo = m + 1; else hi = m; }
    int s = lo;
    hi = nrows;
    while (lo < hi) { int m = (lo + hi) >> 1; if (batch[m] < b + 1) lo = m + 1; else hi = m; }
    int e = lo;
    float acc = 0.f;
    for (int r = s; r < e; r++) {
        size_t row = map ? (size_t)map[r] : (size_t)r;
        acc += src[row * HH + t];
    }
    out[(size_t)b * HH + t] = acc / fmaxf((float)(e - s), 1.f);
}

__global__ void k_seg_mean_bf16(const unsigned short* __restrict__ src,
                                const int* __restrict__ batch, float* __restrict__ out, int nrows) {
    int b = blockIdx.x;
    int t = threadIdx.x;  // 128
    int lo = 0, hi = nrows;
    while (lo < hi) { int m = (lo + hi) >> 1; if (batch[m] < b) lo = m + 1; else hi = m; }
    int s = lo;
    hi = nrows;
    while (lo < hi) { int m = (lo + hi) >> 1; if (batch[m] < b + 1) lo = m + 1; else hi = m; }
    int e = lo;
    float acc = 0.f;
    for (int r = s; r < e; r++) acc += b2f(src[(size_t)r * HH + t]);
    out[(size_t)b * HH + t] = acc / fmaxf((float)(e - s), 1.f);
}

// ---------------- head kernels ----------------
__global__ void k_cond(const float* __restrict__ mctx, const float* __restrict__ mtgt,
                       const int* __restrict__ cidx, const int* __restrict__ tgt_idxs,
                       const float* __restrict__ ppe, const float* __restrict__ Wprw,
                       const float* __restrict__ bprw, float* __restrict__ cond,
                       float* __restrict__ out0) {
    int r = blockIdx.x;   // 0..2047
    int t = threadIdx.x;  // 128
    int bg = r >> 2, tt = r & 3;
    int ti = tgt_idxs[bg * cPT + tt] + bg * cPPG;
    int ci = cidx[bg] + bg * cPPG;
    __shared__ float pe[cPRW];
    if (t < cPRW) pe[t] = ppe[(size_t)ti * cPRW + t];
    __syncthreads();
    float acc = bprw[t];
#pragma unroll
    for (int k = 0; k < cPRW; k++) acc += pe[k] * Wprw[k * HH + t];
    cond[(size_t)r * HH + t] = mctx[(size_t)ci * HH + t] + acc;
    out0[(size_t)r * HH + t] = mtgt[(size_t)ti * HH + t];
}

__global__ void k_gemm_h(const float* __restrict__ x, const float* __restrict__ W,
                         const float* __restrict__ b, float* __restrict__ y) {
    int r = blockIdx.x;
    int t = threadIdx.x;  // 128
    __shared__ float xr[HH];
    xr[t] = x[(size_t)r * HH + t];
    __syncthreads();
    float acc = b[t];
#pragma unroll 8
    for (int k = 0; k < HH; k++) acc += xr[k] * W[k * HH + t];
    y[(size_t)r * HH + t] = acc;
}

__global__ void k_bn_stats(const float* __restrict__ x, float* __restrict__ stats, int rows) {
    int c = blockIdx.x;
    int t = threadIdx.x;  // 256
    float s = 0.f, sq = 0.f;
    for (int r = t; r < rows; r += 256) {
        float v = x[(size_t)r * HH + c];
        s += v; sq += v * v;
    }
    __shared__ float bs[256], bq[256];
    bs[t] = s; bq[t] = sq;
    __syncthreads();
    for (int o = 128; o > 0; o >>= 1) {
        if (t < o) { bs[t] += bs[t + o]; bq[t] += bq[t + o]; }
        __syncthreads();
    }
    if (t == 0) {
        float m = bs[0] / rows;
        float var = bq[0] / rows - m * m;
        stats[c] = m;
        stats[HH + c] = rsqrtf(var + 1e-5f);
    }
}

__global__ void k_bn_relu(float* __restrict__ x, const float* __restrict__ stats,
                          const float* __restrict__ g, const float* __restrict__ be, int rows) {
    int gid = blockIdx.x * 256 + threadIdx.x;
    if (gid >= rows * HH) return;
    int c = gid & 127;
    float v = (x[gid] - stats[c]) * stats[HH + c] * g[c] + be[c];
    x[gid] = fmaxf(v, 0.f);
}

// ---------------- CSR build driver ----------------
static void build_csr(const int* src, const int* dst, const int* emap, int nnodes, int ne,
                      int* rp, int* srcs, int* ais, int* cursor, int* bsum,
                      hipStream_t stream) {
    int nb = (nnodes + 255) / 256;
    k_zero_int<<<nb, 256, 0, stream>>>(cursor, nnodes);
    k_hist<<<(ne + 255) / 256, 256, 0, stream>>>(dst, cursor, ne);
    k_scan_local<<<nb, 256, 0, stream>>>(cursor, rp + 1, bsum, nnodes);
    k_scan_bsums<<<1, 256, 0, stream>>>(bsum, nb);
    k_rp_finalize<<<nb, 256, 0, stream>>>(bsum, rp, nnodes);
    k_copy_int<<<nb, 256, 0, stream>>>(rp, cursor, nnodes);
    k_scatter<<<(ne + 255) / 256, 256, 0, stream>>>(src, dst, emap, cursor, srcs, ais, ne);
}

extern "C" void kernel_launch(void* const* d_in, const int* in_sizes, int n_in,
                              void* d_out, int out_size, void* d_ws, size_t ws_size,
                              hipStream_t stream) {
    (void)in_sizes; (void)n_in;
    const float* x      = (const float*)d_in[0];
    const float* rw     = (const float*)d_in[1];
    const int*   eidx   = (const int*)d_in[3];
    const float* eattr  = (const float*)d_in[4];
    const float* ew     = (const float*)d_in[5];
    const float* ppe    = (const float*)d_in[6];
    const int*   nmap   = (const int*)d_in[7];
    const int*   csub   = (const int*)d_in[8];
    const int*   semap  = (const int*)d_in[9];
    const int*   sbatch = (const int*)d_in[10];
    const int*   cidx   = (const int*)d_in[11];
    const int*   tgts   = (const int*)d_in[12];
    const float* Win  = (const float*)d_in[14]; const float* bin  = (const float*)d_in[15];
    const float* Wrw  = (const float*)d_in[16]; const float* brw  = (const float*)d_in[17];
    const float* Wprw = (const float*)d_in[18]; const float* bprw = (const float*)d_in[19];
    const float* cWe  = (const float*)d_in[20]; const float* cbe  = (const float*)d_in[21];
    const float* cWl  = (const float*)d_in[22]; const float* cbl  = (const float*)d_in[23];
    const float* tWe  = (const float*)d_in[24]; const float* tbe  = (const float*)d_in[25];
    const float* tWl  = (const float*)d_in[26]; const float* tbl  = (const float*)d_in[27];
    const float* Wp1  = (const float*)d_in[28]; const float* bp1  = (const float*)d_in[29];
    const float* g1   = (const float*)d_in[30]; const float* be1  = (const float*)d_in[31];
    const float* Wp2  = (const float*)d_in[32]; const float* bp2  = (const float*)d_in[33];
    const float* g2   = (const float*)d_in[34]; const float* be2  = (const float*)d_in[35];
    const float* Wp3  = (const float*)d_in[36]; const float* bp3  = (const float*)d_in[37];
    float* out = (float*)d_out;

    // ---- workspace layout ----
    const size_t R = (size_t)cN * HH * sizeof(float);  // 102,400,000
    char* base = (char*)d_ws;
    float* R0f = (float*)base;
    float* R1f = (float*)(base + R);
    unsigned short* R0h = (unsigned short*)base;
    unsigned short* R1h = (unsigned short*)(base + R);
    int* ip = (int*)(base + 2 * R);
    int* rp_t  = ip;  ip += cN + 1;
    int* rp_c  = ip;  ip += cNS + 1;
    int* src_t = ip;  ip += cE;
    int* ai_t  = ip;  ip += cE;
    int* src_c = ip;  ip += cES;
    int* ai_c  = ip;  ip += cES;
    int* cursor = ip; ip += cNS;
    int* bsum  = ip;  ip += 2048;
    char* cp = (char*)(((uintptr_t)ip + 15) & ~(uintptr_t)15);
    unsigned short* wfragC  = (unsigned short*)cp;            // 4 x 32768
    unsigned short* wfragTH = wfragC + (size_t)4 * 32768;     // 4 x 32768
    unsigned short* wfragTL = wfragTH + (size_t)4 * 32768;    // 4 x 32768
    cp += (size_t)12 * 32768 * sizeof(unsigned short);
    float* fp  = (float*)cp;
    float* mctx = fp; fp += (size_t)cNP * HH;
    float* mtgt = fp; fp += (size_t)cNP * HH;
    float* bufc = fp; fp += (size_t)2048 * HH;
    float* bufa = fp; fp += (size_t)2048 * HH;
    float* bufb = fp; fp += (size_t)2048 * HH;
    float* stats = fp; fp += 256;
    const size_t need = (size_t)((char*)fp - base);
    if (ws_size < need) {
        k_diag<<<(out_size + 255) / 256, 256, 0, stream>>>(out, out_size,
                                                           (float)(ws_size >> 20));
        return;
    }

    // ---- phase 0: CSRs + W fragments ----
    build_csr(eidx, eidx + cE, nullptr, cN, cE, rp_t, src_t, ai_t, cursor, bsum, stream);
    build_csr(csub, csub + cES, semap, cNS, cES, rp_c, src_c, ai_c, cursor, bsum, stream);
    k_wfrag_all<<<192, 256, 0, stream>>>(cWl, tWl, wfragC, wfragTH, wfragTL);

    // ---- phase 1: target branch, f32 ping-pong R0 <-> R1 ----
    k_node_encode<<<cN, 128, 0, stream>>>(x, rw, Win, bin, Wrw, brw, R0f);
    {
        float* hp[2] = { R0f, R1f };
        for (int l = 0; l < cL; l++) {
            k_layer_tgt<<<cN / 32, 256, 0, stream>>>(
                hp[l & 1], hp[(l & 1) ^ 1], rp_t, src_t, ai_t,
                eattr, ew, tWe, tbe,
                wfragTH + (size_t)l * 32768, wfragTL + (size_t)l * 32768, tbl + l * HH);
        }
    }
    k_seg_mean_f32<<<cNP, 128, 0, stream>>>(R0f, nmap, sbatch, mtgt, cNS);

    // ---- phase 2: context branch, bf16 ping-pong + MFMA ----
    k_encode_gather_bf16<<<cNS, 128, 0, stream>>>(x, rw, nmap, Win, bin, Wrw, brw, R0h);
    {
        unsigned short* hp[2] = { R0h, R1h };
        for (int l = 0; l < cL; l++) {
            k_layer_ctx<<<cNS / 32, 256, 0, stream>>>(
                hp[l & 1], hp[(l & 1) ^ 1], rp_c, src_c, ai_c,
                eattr, ew, cWe, cbe, wfragC + (size_t)l * 32768, cbl + l * HH);
        }
    }
    k_seg_mean_bf16<<<cNP, 128, 0, stream>>>(R0h, sbatch, mctx, cNS);

    // ---- predictor head ----
    k_cond<<<cB * cPT, 128, 0, stream>>>(mctx, mtgt, cidx, tgts, ppe, Wprw, bprw, bufc, out);
    k_gemm_h<<<2048, 128, 0, stream>>>(bufc, Wp1, bp1, bufa);
    k_bn_stats<<<HH, 256, 0, stream>>>(bufa, stats, 2048);
    k_bn_relu<<<(2048 * HH) / 256, 256, 0, stream>>>(bufa, stats, g1, be1, 2048);
    k_gemm_h<<<2048, 128, 0, stream>>>(bufa, Wp2, bp2, bufb);
    k_bn_stats<<<HH, 256, 0, stream>>>(bufb, stats, 2048);
    k_bn_relu<<<(2048 * HH) / 256, 256, 0, stream>>>(bufb, stats, g2, be2, 2048);
    k_gemm_h<<<2048, 128, 0, stream>>>(bufb, Wp3, bp3, out + (size_t)2048 * HH);
}

// Round 10
// 3805.766 us; speedup vs baseline: 2.2983x; 1.1416x over previous
//
#include <hip/hip_runtime.h>

#define HH 128
constexpr int cN   = 200000;
constexpr int cE   = 800000;
constexpr int cNS  = 400000;
constexpr int cES  = 1600000;
constexpr int cB   = 512;
constexpr int cPPG = 8;
constexpr int cPT  = 4;
constexpr int cNP  = cB * cPPG;     // 4096 patches
constexpr int cNF  = 64;
constexpr int cNE  = 16;
constexpr int cRW  = 16;
constexpr int cPRW = 16;
constexpr int cL   = 4;

typedef __attribute__((ext_vector_type(8))) short s16x8;
typedef __attribute__((ext_vector_type(4))) float f32x4;

__device__ __forceinline__ float b2f(unsigned short b) {
    return __uint_as_float(((unsigned int)b) << 16);
}
__device__ __forceinline__ unsigned short f2b(float f) {
    unsigned int u = __float_as_uint(f);
    return (unsigned short)((u + 0x7fffu + ((u >> 16) & 1u)) >> 16);  // RNE
}

// ---------------- diagnostic ----------------
__global__ void k_diag(float* __restrict__ out, int n, float val) {
    int gid = blockIdx.x * 256 + threadIdx.x;
    if (gid < n) out[gid] = val;
}

__global__ void k_zero_int(int* __restrict__ p, int n) {
    int i = blockIdx.x * 256 + threadIdx.x;
    if (i < n) p[i] = 0;
}
__global__ void k_copy_int(const int* __restrict__ a, int* __restrict__ b, int n) {
    int i = blockIdx.x * 256 + threadIdx.x;
    if (i < n) b[i] = a[i];
}

// ---------------- CSR build ----------------
__global__ void k_hist(const int* __restrict__ dst, int* __restrict__ cnt, int ne) {
    int e = blockIdx.x * 256 + threadIdx.x;
    if (e < ne) atomicAdd(&cnt[dst[e]], 1);
}

__global__ void k_scan_local(const int* __restrict__ cnt, int* __restrict__ rp1,
                             int* __restrict__ bsum, int n) {
    __shared__ int s[256];
    int t = threadIdx.x;
    int i = blockIdx.x * 256 + t;
    s[t] = (i < n) ? cnt[i] : 0;
    __syncthreads();
    for (int off = 1; off < 256; off <<= 1) {
        int u = (t >= off) ? s[t - off] : 0;
        __syncthreads();
        s[t] += u;
        __syncthreads();
    }
    if (i < n) rp1[i] = s[t];
    if (t == 255) bsum[blockIdx.x] = s[255];
}

__global__ void k_scan_bsums(int* __restrict__ bsum, int nb) {
    __shared__ int s[256];
    __shared__ int carry;
    int t = threadIdx.x;
    if (t == 0) carry = 0;
    __syncthreads();
    for (int base = 0; base < nb; base += 256) {
        int i = base + t;
        s[t] = (i < nb) ? bsum[i] : 0;
        __syncthreads();
        for (int off = 1; off < 256; off <<= 1) {
            int u = (t >= off) ? s[t - off] : 0;
            __syncthreads();
            s[t] += u;
            __syncthreads();
        }
        int c = carry;
        if (i < nb) bsum[i] = s[t] + c;
        __syncthreads();
        if (t == 0) carry = c + s[255];
        __syncthreads();
    }
}

__global__ void k_rp_finalize(const int* __restrict__ bsum, int* __restrict__ rp, int n) {
    int i = blockIdx.x * 256 + threadIdx.x;
    if (i == 0) rp[0] = 0;
    if (i < n) {
        int blk = i >> 8;
        rp[i + 1] += blk ? bsum[blk - 1] : 0;
    }
}

__global__ void k_scatter(const int* __restrict__ src, const int* __restrict__ dst,
                          const int* __restrict__ emap, int* __restrict__ cursor,
                          int* __restrict__ srcs, int* __restrict__ ais, int ne) {
    int e = blockIdx.x * 256 + threadIdx.x;
    if (e >= ne) return;
    int d = dst[e];
    int p = atomicAdd(&cursor[d], 1);
    srcs[p] = src[e];
    ais[p] = emap ? emap[e] : e;
}

// ---------------- W -> bf16 MFMA fragments: 4 ctx (hi), 4 tgt hi, 4 tgt lo ----------------
__global__ void k_wfrag_all(const float* __restrict__ cWl, const float* __restrict__ tWl,
                            unsigned short* __restrict__ fC, unsigned short* __restrict__ fTH,
                            unsigned short* __restrict__ fTL) {
    int g = blockIdx.x * 256 + threadIdx.x;   // 12 * 4096
    int set = g >> 12;
    int r = g & 4095;
    int ct = r >> 9, ks = (r >> 6) & 7, lane = r & 63;
    const float* W;
    unsigned short* outp;
    bool lo = false;
    if (set < 4)      { W = cWl + (size_t)set * 2 * HH * HH;       outp = fC  + (size_t)set * 32768; }
    else if (set < 8) { W = tWl + (size_t)(set - 4) * 2 * HH * HH; outp = fTH + (size_t)(set - 4) * 32768; }
    else              { W = tWl + (size_t)(set - 8) * 2 * HH * HH; outp = fTL + (size_t)(set - 8) * 32768; lo = true; }
#pragma unroll
    for (int j = 0; j < 8; j++) {
        float w = W[(size_t)(ks * 32 + (lane >> 4) * 8 + j) * HH + ct * 16 + (lane & 15)];
        unsigned short hi = f2b(w);
        outp[(size_t)r * 8 + j] = lo ? f2b(w - b2f(hi)) : hi;
    }
}

// ---------------- node encoder, 16 nodes/block: out = enc(x[map[i]], rw[map[i]]) ----------------
// BF16OUT=false, map=nullptr -> f32 out identity; BF16OUT=true -> bf16 out gathered
template <bool BF16OUT>
__global__ void __launch_bounds__(256)
k_encode16(const float* __restrict__ x, const float* __restrict__ rw,
           const int* __restrict__ map,
           const float* __restrict__ Win, const float* __restrict__ bin,
           const float* __restrict__ Wrw, const float* __restrict__ brw,
           void* __restrict__ outv) {
    __shared__ float sx[16][cNF];
    __shared__ float srw[16][cRW];
    int t = threadIdx.x;
    int nb = blockIdx.x * 16;
    // stage: thread t -> node n=t>>4, float4 slot v=t&15
    {
        int n = t >> 4, v = t & 15;
        int node = map ? map[nb + n] : (nb + n);
        ((float4*)&sx[n][0])[v] = ((const float4*)&x[(size_t)node * cNF])[v];
        if (v < 4) ((float4*)&srw[n][0])[v] = ((const float4*)&rw[(size_t)node * cRW])[v];
    }
    // hoist this thread's fixed weight column c = t&127 (reused for all 8 outputs)
    int c = t & 127;
    float wcol[cNF], wrcol[cRW];
#pragma unroll
    for (int k = 0; k < cNF; k++) wcol[k] = Win[k * HH + c];
#pragma unroll
    for (int k = 0; k < cRW; k++) wrcol[k] = Wrw[k * HH + c];
    float bsum = bin[c] + brw[c];
    __syncthreads();

#pragma unroll
    for (int p = 0; p < 8; p++) {
        int n = (p * 256 + t) >> 7;     // wave-uniform
        float acc = bsum;
#pragma unroll
        for (int k = 0; k < cNF; k += 4) {
            float4 s4 = *(const float4*)&sx[n][k];
            acc += s4.x * wcol[k] + s4.y * wcol[k + 1] + s4.z * wcol[k + 2] + s4.w * wcol[k + 3];
        }
#pragma unroll
        for (int k = 0; k < cRW; k += 4) {
            float4 s4 = *(const float4*)&srw[n][k];
            acc += s4.x * wrcol[k] + s4.y * wrcol[k + 1] + s4.z * wrcol[k + 2] + s4.w * wrcol[k + 3];
        }
        size_t oidx = (size_t)(nb + n) * HH + c;
        if (BF16OUT) ((unsigned short*)outv)[oidx] = f2b(acc);
        else         ((float*)outv)[oidx] = acc;
    }
}

// ---------------- ctx layer: edge-parallel agg + bf16 MFMA; LDS union, 26 KB ----------------
__global__ void __launch_bounds__(256)
k_layer_ctx(const unsigned short* __restrict__ h_in, unsigned short* __restrict__ h_out,
            const int* __restrict__ rp, const int* __restrict__ srcs,
            const int* __restrict__ ais,
            const float* __restrict__ eattr, const float* __restrict__ ew,
            const float* __restrict__ We, const float* __restrict__ be,
            const unsigned short* __restrict__ Wfrag, const float* __restrict__ bias) {
    __shared__ unsigned short pool[8448];   // union: msg[64][130] (16640B) | At[32][264] (16896B)
    __shared__ float WeL[16][128];
    __shared__ float beL[128];
    __shared__ float wsl[64];
    auto msg = (unsigned short (*)[130])pool;
    auto At  = (unsigned short (*)[264])pool;
    int t = threadIdx.x;
    int base = blockIdx.x * 32;

    for (int i = t; i < 2048; i += 256) WeL[i >> 7][i & 127] = We[i];
    if (t < 128) beL[t] = be[t];
    int eblk0 = rp[base], eblk1 = rp[base + 32];
    int prow = t >> 3, pch = (t & 7) * 16;
    int re0 = rp[base + prow], re1 = rp[base + prow + 1];
    float acc[16];
#pragma unroll
    for (int j = 0; j < 16; j++) acc[j] = 0.f;
    __syncthreads();

    for (int cs = eblk0; cs < eblk1; cs += 64) {
        int ce = min(cs + 64, eblk1);
        // phase 1: slot = t&63 (64 lanes = 64 distinct slots -> 2-way banks), q = t>>6
        {
            int slot = t & 63, q = t >> 6;
            int e = cs + slot;
            if (e < ce) {
                int ai = ais[e];
                if (q == 0) wsl[slot] = ew[ai];
                const float* ea = eattr + (size_t)ai * cNE;
                float eav[16];
#pragma unroll
                for (int k = 0; k < 16; k += 4) *(float4*)&eav[k] = *(const float4*)&ea[k];
                int c0 = q * 32;
                float m[32];
#pragma unroll
                for (int c = 0; c < 32; c++) m[c] = beL[c0 + c];
#pragma unroll
                for (int k = 0; k < 16; k++) {
                    float ev = eav[k];
#pragma unroll
                    for (int c = 0; c < 32; c++) m[c] += ev * WeL[k][c0 + c];
                }
#pragma unroll
                for (int c = 0; c < 32; c++) msg[slot][c0 + c] = f2b(fmaxf(m[c], 0.f));
            }
        }
        __syncthreads();
        // phase 2: thread = (row, 16-ch slice), f32 register accum
        {
            int e0 = max(re0, cs), e1 = min(re1, ce);
            for (int e = e0; e < e1; e++) {
                int sl = e - cs;
                float w = wsl[sl];
                int s = srcs[e];
                const unsigned short* hrow = &h_in[(size_t)s * HH + pch];
#pragma unroll
                for (int j = 0; j < 16; j += 2) {
                    unsigned int hv = *(const unsigned int*)&hrow[j];
                    unsigned int mv = *(const unsigned int*)&msg[sl][pch + j];
                    acc[j]     += (b2f((unsigned short)hv) + b2f((unsigned short)mv)) * w;
                    acc[j + 1] += (b2f((unsigned short)(hv >> 16)) +
                                   b2f((unsigned short)(mv >> 16))) * w;
                }
            }
        }
        __syncthreads();
    }
    // build A-tile (msg is dead): agg half from registers, own-h half from global
#pragma unroll
    for (int j = 0; j < 16; j++) At[prow][HH + pch + j] = f2b(acc[j]);
    for (int i = t; i < 512; i += 256) {
        int r = i >> 4, cc = (i & 15) * 8;
        *(s16x8*)&At[r][cc] = *(const s16x8*)&h_in[(size_t)(base + r) * HH + cc];
    }
    __syncthreads();

    // MFMA: wave wv -> col-tiles 2wv,2wv+1; row-tiles 0,1; K=256 in 8 steps
    int lane = t & 63, wv = t >> 6;
    f32x4 ac[2][2];
#pragma unroll
    for (int i1 = 0; i1 < 2; i1++)
#pragma unroll
        for (int i2 = 0; i2 < 2; i2++) ac[i1][i2] = (f32x4)(0.f);
    int ar = lane & 15, g4 = lane >> 4;
#pragma unroll
    for (int ks = 0; ks < 8; ks++) {
        int ak = ks * 32 + g4 * 8;
        s16x8 a0 = *(const s16x8*)&At[ar][ak];
        s16x8 a1 = *(const s16x8*)&At[16 + ar][ak];
#pragma unroll
        for (int q = 0; q < 2; q++) {
            int ct = 2 * wv + q;
            s16x8 bq = *(const s16x8*)&Wfrag[((size_t)(ct * 8 + ks) * 64 + lane) * 8];
            ac[0][q] = __builtin_amdgcn_mfma_f32_16x16x32_bf16(a0, bq, ac[0][q], 0, 0, 0);
            ac[1][q] = __builtin_amdgcn_mfma_f32_16x16x32_bf16(a1, bq, ac[1][q], 0, 0, 0);
        }
    }
#pragma unroll
    for (int rt = 0; rt < 2; rt++)
#pragma unroll
        for (int q = 0; q < 2; q++) {
            int col = (2 * wv + q) * 16 + ar;
            float bv = bias[col];
#pragma unroll
            for (int qi = 0; qi < 4; qi++) {
                int row = base + rt * 16 + g4 * 4 + qi;
                h_out[(size_t)row * HH + col] = f2b(fmaxf(ac[rt][q][qi] + bv, 0.f));
            }
        }
}

// ---------------- tgt layer: edge-parallel agg + bf16x3 MFMA GEMM (f32-accurate) ----------------
__global__ void __launch_bounds__(256)
k_layer_tgt(const float* __restrict__ h_in, float* __restrict__ h_out,
            const int* __restrict__ rp, const int* __restrict__ srcs,
            const int* __restrict__ ais,
            const float* __restrict__ eattr, const float* __restrict__ ew,
            const float* __restrict__ We, const float* __restrict__ be,
            const unsigned short* __restrict__ WfH, const unsigned short* __restrict__ WfL,
            const float* __restrict__ bias) {
    __shared__ unsigned short pool[16896];  // union: msg f32[64][129] (33024B) | At_hi+At_lo (33792B)
    __shared__ float WeL[16][128];
    __shared__ float beL[128];
    __shared__ float wsl[64];
    auto msg  = (float (*)[129])pool;
    auto AtH  = (unsigned short (*)[264])pool;
    auto AtL  = (unsigned short (*)[264])(pool + 8448);
    int t = threadIdx.x;
    int base = blockIdx.x * 32;

    for (int i = t; i < 2048; i += 256) WeL[i >> 7][i & 127] = We[i];
    if (t < 128) beL[t] = be[t];
    int eblk0 = rp[base], eblk1 = rp[base + 32];
    int prow = t >> 3, pch = (t & 7) * 16;
    int re0 = rp[base + prow], re1 = rp[base + prow + 1];
    float acc[16];
#pragma unroll
    for (int j = 0; j < 16; j++) acc[j] = 0.f;
    __syncthreads();

    for (int cs = eblk0; cs < eblk1; cs += 64) {
        int ce = min(cs + 64, eblk1);
        {
            int slot = t & 63, q = t >> 6;
            int e = cs + slot;
            if (e < ce) {
                int ai = ais[e];
                if (q == 0) wsl[slot] = ew[ai];
                const float* ea = eattr + (size_t)ai * cNE;
                float eav[16];
#pragma unroll
                for (int k = 0; k < 16; k += 4) *(float4*)&eav[k] = *(const float4*)&ea[k];
                int c0 = q * 32;
                float m[32];
#pragma unroll
                for (int c = 0; c < 32; c++) m[c] = beL[c0 + c];
#pragma unroll
                for (int k = 0; k < 16; k++) {
                    float ev = eav[k];
#pragma unroll
                    for (int c = 0; c < 32; c++) m[c] += ev * WeL[k][c0 + c];
                }
#pragma unroll
                for (int c = 0; c < 32; c++) msg[slot][c0 + c] = fmaxf(m[c], 0.f);
            }
        }
        __syncthreads();
        {
            int e0 = max(re0, cs), e1 = min(re1, ce);
            for (int e = e0; e < e1; e++) {
                int sl = e - cs;
                float w = wsl[sl];
                int s = srcs[e];
                const float* hrow = &h_in[(size_t)s * HH + pch];
#pragma unroll
                for (int j = 0; j < 16; j += 4) {
                    float4 hv = *(const float4*)&hrow[j];
                    acc[j]     += (hv.x + msg[sl][pch + j])     * w;
                    acc[j + 1] += (hv.y + msg[sl][pch + j + 1]) * w;
                    acc[j + 2] += (hv.z + msg[sl][pch + j + 2]) * w;
                    acc[j + 3] += (hv.w + msg[sl][pch + j + 3]) * w;
                }
            }
        }
        __syncthreads();
    }
    // build hi/lo split A-tile (msg dead)
#pragma unroll
    for (int j = 0; j < 16; j++) {
        float v = acc[j];
        unsigned short hi = f2b(v);
        AtH[prow][HH + pch + j] = hi;
        AtL[prow][HH + pch + j] = f2b(v - b2f(hi));
    }
    for (int i = t; i < 32 * HH; i += 256) {
        int r = i >> 7, c = i & 127;
        float v = h_in[(size_t)(base + r) * HH + c];
        unsigned short hi = f2b(v);
        AtH[r][c] = hi;
        AtL[r][c] = f2b(v - b2f(hi));
    }
    __syncthreads();

    // bf16x3 MFMA: acc = aH*bH + aL*bH + aH*bL  (error ~2^-16 relative)
    int lane = t & 63, wv = t >> 6;
    f32x4 ac[2][2];
#pragma unroll
    for (int i1 = 0; i1 < 2; i1++)
#pragma unroll
        for (int i2 = 0; i2 < 2; i2++) ac[i1][i2] = (f32x4)(0.f);
    int ar = lane & 15, g4 = lane >> 4;
#pragma unroll
    for (int ks = 0; ks < 8; ks++) {
        int ak = ks * 32 + g4 * 8;
        s16x8 a0h = *(const s16x8*)&AtH[ar][ak];
        s16x8 a1h = *(const s16x8*)&AtH[16 + ar][ak];
        s16x8 a0l = *(const s16x8*)&AtL[ar][ak];
        s16x8 a1l = *(const s16x8*)&AtL[16 + ar][ak];
#pragma unroll
        for (int q = 0; q < 2; q++) {
            int ct = 2 * wv + q;
            size_t fo = ((size_t)(ct * 8 + ks) * 64 + lane) * 8;
            s16x8 bh = *(const s16x8*)&WfH[fo];
            s16x8 bl = *(const s16x8*)&WfL[fo];
            ac[0][q] = __builtin_amdgcn_mfma_f32_16x16x32_bf16(a0h, bh, ac[0][q], 0, 0, 0);
            ac[0][q] = __builtin_amdgcn_mfma_f32_16x16x32_bf16(a0l, bh, ac[0][q], 0, 0, 0);
            ac[0][q] = __builtin_amdgcn_mfma_f32_16x16x32_bf16(a0h, bl, ac[0][q], 0, 0, 0);
            ac[1][q] = __builtin_amdgcn_mfma_f32_16x16x32_bf16(a1h, bh, ac[1][q], 0, 0, 0);
            ac[1][q] = __builtin_amdgcn_mfma_f32_16x16x32_bf16(a1l, bh, ac[1][q], 0, 0, 0);
            ac[1][q] = __builtin_amdgcn_mfma_f32_16x16x32_bf16(a1h, bl, ac[1][q], 0, 0, 0);
        }
    }
#pragma unroll
    for (int rt = 0; rt < 2; rt++)
#pragma unroll
        for (int q = 0; q < 2; q++) {
            int col = (2 * wv + q) * 16 + ar;
            float bv = bias[col];
#pragma unroll
            for (int qi = 0; qi < 4; qi++) {
                int row = base + rt * 16 + g4 * 4 + qi;
                h_out[(size_t)row * HH + col] = fmaxf(ac[rt][q][qi] + bv, 0.f);
            }
        }
}

// ---------------- segmented mean over sorted batch ----------------
__global__ void k_seg_mean_f32(const float* __restrict__ src, const int* __restrict__ map,
                               const int* __restrict__ batch, float* __restrict__ out, int nrows) {
    int b = blockIdx.x;
    int t = threadIdx.x;  // 128
    int lo = 0, hi = nrows;
    while (lo < hi) { int m = (lo + hi) >> 1; if (batch[m] < b) lo = m + 1; else hi = m; }
    int s = lo;
    hi = nrows;
    while (lo < hi) { int m = (lo + hi) >> 1; if (batch[m] < b + 1) lo = m + 1; else hi = m; }
    int e = lo;
    float acc = 0.f;
    for (int r = s; r < e; r++) {
        size_t row = map ? (size_t)map[r] : (size_t)r;
        acc += src[row * HH + t];
    }
    out[(size_t)b * HH + t] = acc / fmaxf((float)(e - s), 1.f);
}

__global__ void k_seg_mean_bf16(const unsigned short* __restrict__ src,
                                const int* __restrict__ batch, float* __restrict__ out, int nrows) {
    int b = blockIdx.x;
    int t = threadIdx.x;  // 128
    int lo = 0, hi = nrows;
    while (lo < hi) { int m = (lo + hi) >> 1; if (batch[m] < b) lo = m + 1; else hi = m; }
    int s = lo;
    hi = nrows;
    while (lo < hi) { int m = (lo + hi) >> 1; if (batch[m] < b + 1) lo = m + 1; else hi = m; }
    int e = lo;
    float acc = 0.f;
    for (int r = s; r < e; r++) acc += b2f(src[(size_t)r * HH + t]);
    out[(size_t)b * HH + t] = acc / fmaxf((float)(e - s), 1.f);
}

// ---------------- head kernels ----------------
__global__ void k_cond(const float* __restrict__ mctx, const float* __restrict__ mtgt,
                       const int* __restrict__ cidx, const int* __restrict__ tgt_idxs,
                       const float* __restrict__ ppe, const float* __restrict__ Wprw,
                       const float* __restrict__ bprw, float* __restrict__ cond,
                       float* __restrict__ out0) {
    int r = blockIdx.x;   // 0..2047
    int t = threadIdx.x;  // 128
    int bg = r >> 2, tt = r & 3;
    int ti = tgt_idxs[bg * cPT + tt] + bg * cPPG;
    int ci = cidx[bg] + bg * cPPG;
    __shared__ float pe[cPRW];
    if (t < cPRW) pe[t] = ppe[(size_t)ti * cPRW + t];
    __syncthreads();
    float acc = bprw[t];
#pragma unroll
    for (int k = 0; k < cPRW; k++) acc += pe[k] * Wprw[k * HH + t];
    cond[(size_t)r * HH + t] = mctx[(size_t)ci * HH + t] + acc;
    out0[(size_t)r * HH + t] = mtgt[(size_t)ti * HH + t];
}

__global__ void k_gemm_h(const float* __restrict__ x, const float* __restrict__ W,
                         const float* __restrict__ b, float* __restrict__ y) {
    int r = blockIdx.x;
    int t = threadIdx.x;  // 128
    __shared__ float xr[HH];
    xr[t] = x[(size_t)r * HH + t];
    __syncthreads();
    float acc = b[t];
#pragma unroll 8
    for (int k = 0; k < HH; k++) acc += xr[k] * W[k * HH + t];
    y[(size_t)r * HH + t] = acc;
}

__global__ void k_bn_stats(const float* __restrict__ x, float* __restrict__ stats, int rows) {
    int c = blockIdx.x;
    int t = threadIdx.x;  // 256
    float s = 0.f, sq = 0.f;
    for (int r = t; r < rows; r += 256) {
        float v = x[(size_t)r * HH + c];
        s += v; sq += v * v;
    }
    __shared__ float bs[256], bq[256];
    bs[t] = s; bq[t] = sq;
    __syncthreads();
    for (int o = 128; o > 0; o >>= 1) {
        if (t < o) { bs[t] += bs[t + o]; bq[t] += bq[t + o]; }
        __syncthreads();
    }
    if (t == 0) {
        float m = bs[0] / rows;
        float var = bq[0] / rows - m * m;
        stats[c] = m;
        stats[HH + c] = rsqrtf(var + 1e-5f);
    }
}

__global__ void k_bn_relu(float* __restrict__ x, const float* __restrict__ stats,
                          const float* __restrict__ g, const float* __restrict__ be, int rows) {
    int gid = blockIdx.x * 256 + threadIdx.x;
    if (gid >= rows * HH) return;
    int c = gid & 127;
    float v = (x[gid] - stats[c]) * stats[HH + c] * g[c] + be[c];
    x[gid] = fmaxf(v, 0.f);
}

// ---------------- CSR build driver ----------------
static void build_csr(const int* src, const int* dst, const int* emap, int nnodes, int ne,
                      int* rp, int* srcs, int* ais, int* cursor, int* bsum,
                      hipStream_t stream) {
    int nb = (nnodes + 255) / 256;
    k_zero_int<<<nb, 256, 0, stream>>>(cursor, nnodes);
    k_hist<<<(ne + 255) / 256, 256, 0, stream>>>(dst, cursor, ne);
    k_scan_local<<<nb, 256, 0, stream>>>(cursor, rp + 1, bsum, nnodes);
    k_scan_bsums<<<1, 256, 0, stream>>>(bsum, nb);
    k_rp_finalize<<<nb, 256, 0, stream>>>(bsum, rp, nnodes);
    k_copy_int<<<nb, 256, 0, stream>>>(rp, cursor, nnodes);
    k_scatter<<<(ne + 255) / 256, 256, 0, stream>>>(src, dst, emap, cursor, srcs, ais, ne);
}

extern "C" void kernel_launch(void* const* d_in, const int* in_sizes, int n_in,
                              void* d_out, int out_size, void* d_ws, size_t ws_size,
                              hipStream_t stream) {
    (void)in_sizes; (void)n_in;
    const float* x      = (const float*)d_in[0];
    const float* rw     = (const float*)d_in[1];
    const int*   eidx   = (const int*)d_in[3];
    const float* eattr  = (const float*)d_in[4];
    const float* ew     = (const float*)d_in[5];
    const float* ppe    = (const float*)d_in[6];
    const int*   nmap   = (const int*)d_in[7];
    const int*   csub   = (const int*)d_in[8];
    const int*   semap  = (const int*)d_in[9];
    const int*   sbatch = (const int*)d_in[10];
    const int*   cidx   = (const int*)d_in[11];
    const int*   tgts   = (const int*)d_in[12];
    const float* Win  = (const float*)d_in[14]; const float* bin  = (const float*)d_in[15];
    const float* Wrw  = (const float*)d_in[16]; const float* brw  = (const float*)d_in[17];
    const float* Wprw = (const float*)d_in[18]; const float* bprw = (const float*)d_in[19];
    const float* cWe  = (const float*)d_in[20]; const float* cbe  = (const float*)d_in[21];
    const float* cWl  = (const float*)d_in[22]; const float* cbl  = (const float*)d_in[23];
    const float* tWe  = (const float*)d_in[24]; const float* tbe  = (const float*)d_in[25];
    const float* tWl  = (const float*)d_in[26]; const float* tbl  = (const float*)d_in[27];
    const float* Wp1  = (const float*)d_in[28]; const float* bp1  = (const float*)d_in[29];
    const float* g1   = (const float*)d_in[30]; const float* be1  = (const float*)d_in[31];
    const float* Wp2  = (const float*)d_in[32]; const float* bp2  = (const float*)d_in[33];
    const float* g2   = (const float*)d_in[34]; const float* be2  = (const float*)d_in[35];
    const float* Wp3  = (const float*)d_in[36]; const float* bp3  = (const float*)d_in[37];
    float* out = (float*)d_out;

    // ---- workspace layout ----
    const size_t R = (size_t)cN * HH * sizeof(float);  // 102,400,000
    char* base = (char*)d_ws;
    float* R0f = (float*)base;
    float* R1f = (float*)(base + R);
    unsigned short* R0h = (unsigned short*)base;
    unsigned short* R1h = (unsigned short*)(base + R);
    int* ip = (int*)(base + 2 * R);
    int* rp_t  = ip;  ip += cN + 1;
    int* rp_c  = ip;  ip += cNS + 1;
    int* src_t = ip;  ip += cE;
    int* ai_t  = ip;  ip += cE;
    int* src_c = ip;  ip += cES;
    int* ai_c  = ip;  ip += cES;
    int* cursor = ip; ip += cNS;
    int* bsum  = ip;  ip += 2048;
    char* cp = (char*)(((uintptr_t)ip + 15) & ~(uintptr_t)15);
    unsigned short* wfragC  = (unsigned short*)cp;            // 4 x 32768
    unsigned short* wfragTH = wfragC + (size_t)4 * 32768;     // 4 x 32768
    unsigned short* wfragTL = wfragTH + (size_t)4 * 32768;    // 4 x 32768
    cp += (size_t)12 * 32768 * sizeof(unsigned short);
    float* fp  = (float*)cp;
    float* mctx = fp; fp += (size_t)cNP * HH;
    float* mtgt = fp; fp += (size_t)cNP * HH;
    float* bufc = fp; fp += (size_t)2048 * HH;
    float* bufa = fp; fp += (size_t)2048 * HH;
    float* bufb = fp; fp += (size_t)2048 * HH;
    float* stats = fp; fp += 256;
    const size_t need = (size_t)((char*)fp - base);
    if (ws_size < need) {
        k_diag<<<(out_size + 255) / 256, 256, 0, stream>>>(out, out_size,
                                                           (float)(ws_size >> 20));
        return;
    }

    // ---- phase 0: CSRs + W fragments ----
    build_csr(eidx, eidx + cE, nullptr, cN, cE, rp_t, src_t, ai_t, cursor, bsum, stream);
    build_csr(csub, csub + cES, semap, cNS, cES, rp_c, src_c, ai_c, cursor, bsum, stream);
    k_wfrag_all<<<192, 256, 0, stream>>>(cWl, tWl, wfragC, wfragTH, wfragTL);

    // ---- phase 1: target branch, f32 ping-pong R0 <-> R1 ----
    k_encode16<false><<<cN / 16, 256, 0, stream>>>(x, rw, nullptr, Win, bin, Wrw, brw, R0f);
    {
        float* hp[2] = { R0f, R1f };
        for (int l = 0; l < cL; l++) {
            k_layer_tgt<<<cN / 32, 256, 0, stream>>>(
                hp[l & 1], hp[(l & 1) ^ 1], rp_t, src_t, ai_t,
                eattr, ew, tWe, tbe,
                wfragTH + (size_t)l * 32768, wfragTL + (size_t)l * 32768, tbl + l * HH);
        }
    }
    k_seg_mean_f32<<<cNP, 128, 0, stream>>>(R0f, nmap, sbatch, mtgt, cNS);

    // ---- phase 2: context branch, bf16 ping-pong + MFMA ----
    k_encode16<true><<<cNS / 16, 256, 0, stream>>>(x, rw, nmap, Win, bin, Wrw, brw, R0h);
    {
        unsigned short* hp[2] = { R0h, R1h };
        for (int l = 0; l < cL; l++) {
            k_layer_ctx<<<cNS / 32, 256, 0, stream>>>(
                hp[l & 1], hp[(l & 1) ^ 1], rp_c, src_c, ai_c,
                eattr, ew, cWe, cbe, wfragC + (size_t)l * 32768, cbl + l * HH);
        }
    }
    k_seg_mean_bf16<<<cNP, 128, 0, stream>>>(R0h, sbatch, mctx, cNS);

    // ---- predictor head ----
    k_cond<<<cB * cPT, 128, 0, stream>>>(mctx, mtgt, cidx, tgts, ppe, Wprw, bprw, bufc, out);
    k_gemm_h<<<2048, 128, 0, stream>>>(bufc, Wp1, bp1, bufa);
    k_bn_stats<<<HH, 256, 0, stream>>>(bufa, stats, 2048);
    k_bn_relu<<<(2048 * HH) / 256, 256, 0, stream>>>(bufa, stats, g1, be1, 2048);
    k_gemm_h<<<2048, 128, 0, stream>>>(bufa, Wp2, bp2, bufb);
    k_bn_stats<<<HH, 256, 0, stream>>>(bufb, stats, 2048);
    k_bn_relu<<<(2048 * HH) / 256, 256, 0, stream>>>(bufb, stats, g2, be2, 2048);
    k_gemm_h<<<2048, 128, 0, stream>>>(bufb, Wp3, bp3, out + (size_t)2048 * HH);
}

// Round 12
// 3092.538 us; speedup vs baseline: 2.8283x; 1.2306x over previous
//
#include <hip/hip_runtime.h>

#define HH 128
constexpr int cN   = 200000;
constexpr int cE   = 800000;
constexpr int cNS  = 400000;
constexpr int cES  = 1600000;
constexpr int cB   = 512;
constexpr int cPPG = 8;
constexpr int cPT  = 4;
constexpr int cNP  = cB * cPPG;     // 4096 patches
constexpr int cNF  = 64;
constexpr int cNE  = 16;
constexpr int cRW  = 16;
constexpr int cPRW = 16;
constexpr int cL   = 4;

typedef __attribute__((ext_vector_type(8))) short s16x8;
typedef __attribute__((ext_vector_type(4))) float f32x4;

__device__ __forceinline__ float b2f(unsigned short b) {
    return __uint_as_float(((unsigned int)b) << 16);
}
__device__ __forceinline__ unsigned short f2b(float f) {
    unsigned int u = __float_as_uint(f);
    return (unsigned short)((u + 0x7fffu + ((u >> 16) & 1u)) >> 16);  // RNE
}

// ---------------- diagnostic ----------------
__global__ void k_diag(float* __restrict__ out, int n, float val) {
    int gid = blockIdx.x * 256 + threadIdx.x;
    if (gid < n) out[gid] = val;
}

__global__ void k_zero_int(int* __restrict__ p, int n) {
    int i = blockIdx.x * 256 + threadIdx.x;
    if (i < n) p[i] = 0;
}
__global__ void k_copy_int(const int* __restrict__ a, int* __restrict__ b, int n) {
    int i = blockIdx.x * 256 + threadIdx.x;
    if (i < n) b[i] = a[i];
}

// ---------------- CSR build ----------------
__global__ void k_hist(const int* __restrict__ dst, int* __restrict__ cnt, int ne) {
    int e = blockIdx.x * 256 + threadIdx.x;
    if (e < ne) atomicAdd(&cnt[dst[e]], 1);
}

__global__ void k_scan_local(const int* __restrict__ cnt, int* __restrict__ rp1,
                             int* __restrict__ bsum, int n) {
    __shared__ int s[256];
    int t = threadIdx.x;
    int i = blockIdx.x * 256 + t;
    s[t] = (i < n) ? cnt[i] : 0;
    __syncthreads();
    for (int off = 1; off < 256; off <<= 1) {
        int u = (t >= off) ? s[t - off] : 0;
        __syncthreads();
        s[t] += u;
        __syncthreads();
    }
    if (i < n) rp1[i] = s[t];
    if (t == 255) bsum[blockIdx.x] = s[255];
}

__global__ void k_scan_bsums(int* __restrict__ bsum, int nb) {
    __shared__ int s[256];
    __shared__ int carry;
    int t = threadIdx.x;
    if (t == 0) carry = 0;
    __syncthreads();
    for (int base = 0; base < nb; base += 256) {
        int i = base + t;
        s[t] = (i < nb) ? bsum[i] : 0;
        __syncthreads();
        for (int off = 1; off < 256; off <<= 1) {
            int u = (t >= off) ? s[t - off] : 0;
            __syncthreads();
            s[t] += u;
            __syncthreads();
        }
        int c = carry;
        if (i < nb) bsum[i] = s[t] + c;
        __syncthreads();
        if (t == 0) carry = c + s[255];
        __syncthreads();
    }
}

__global__ void k_rp_finalize(const int* __restrict__ bsum, int* __restrict__ rp, int n) {
    int i = blockIdx.x * 256 + threadIdx.x;
    if (i == 0) rp[0] = 0;
    if (i < n) {
        int blk = i >> 8;
        rp[i + 1] += blk ? bsum[blk - 1] : 0;
    }
}

__global__ void k_scatter(const int* __restrict__ src, const int* __restrict__ dst,
                          const int* __restrict__ emap, int* __restrict__ cursor,
                          int* __restrict__ srcs, int* __restrict__ ais, int ne) {
    int e = blockIdx.x * 256 + threadIdx.x;
    if (e >= ne) return;
    int d = dst[e];
    int p = atomicAdd(&cursor[d], 1);
    srcs[p] = src[e];
    ais[p] = emap ? emap[e] : e;
}

// ---------------- W -> bf16 MFMA fragments: 4 ctx hi, 4 tgt hi, 4 tgt lo, ctx We-frag ----------------
__global__ void k_wfrag_all(const float* __restrict__ cWl, const float* __restrict__ tWl,
                            const float* __restrict__ cWe,
                            unsigned short* __restrict__ fC, unsigned short* __restrict__ fTH,
                            unsigned short* __restrict__ fTL, unsigned short* __restrict__ wez) {
    int g = blockIdx.x * 256 + threadIdx.x;   // 13 * 4096
    int set = g >> 12;
    int r = g & 4095;
    if (set == 12) {
        // ctx We fragments, zero-padded K 16->32: [ct][lane][j]
        if (r < 512) {
            int ct = r >> 6, lane = r & 63;
#pragma unroll
            for (int j = 0; j < 8; j++) {
                int k = (lane >> 4) * 8 + j;
                wez[((size_t)ct * 64 + lane) * 8 + j] =
                    (k < 16) ? f2b(cWe[k * HH + ct * 16 + (lane & 15)]) : (unsigned short)0;
            }
        }
        return;
    }
    int ct = r >> 9, ks = (r >> 6) & 7, lane = r & 63;
    const float* W;
    unsigned short* outp;
    bool lo = false;
    if (set < 4)      { W = cWl + (size_t)set * 2 * HH * HH;       outp = fC  + (size_t)set * 32768; }
    else if (set < 8) { W = tWl + (size_t)(set - 4) * 2 * HH * HH; outp = fTH + (size_t)(set - 4) * 32768; }
    else              { W = tWl + (size_t)(set - 8) * 2 * HH * HH; outp = fTL + (size_t)(set - 8) * 32768; lo = true; }
#pragma unroll
    for (int j = 0; j < 8; j++) {
        float w = W[(size_t)(ks * 32 + (lane >> 4) * 8 + j) * HH + ct * 16 + (lane & 15)];
        unsigned short hi = f2b(w);
        outp[(size_t)r * 8 + j] = lo ? f2b(w - b2f(hi)) : hi;
    }
}

// ---------------- node encoder, 16 nodes/block ----------------
template <bool BF16OUT>
__global__ void __launch_bounds__(256)
k_encode16(const float* __restrict__ x, const float* __restrict__ rw,
           const int* __restrict__ map,
           const float* __restrict__ Win, const float* __restrict__ bin,
           const float* __restrict__ Wrw, const float* __restrict__ brw,
           void* __restrict__ outv) {
    __shared__ float sx[16][cNF];
    __shared__ float srw[16][cRW];
    int t = threadIdx.x;
    int nb = blockIdx.x * 16;
    {
        int n = t >> 4, v = t & 15;
        int node = map ? map[nb + n] : (nb + n);
        ((float4*)&sx[n][0])[v] = ((const float4*)&x[(size_t)node * cNF])[v];
        if (v < 4) ((float4*)&srw[n][0])[v] = ((const float4*)&rw[(size_t)node * cRW])[v];
    }
    int c = t & 127;
    float wcol[cNF], wrcol[cRW];
#pragma unroll
    for (int k = 0; k < cNF; k++) wcol[k] = Win[k * HH + c];
#pragma unroll
    for (int k = 0; k < cRW; k++) wrcol[k] = Wrw[k * HH + c];
    float bsum = bin[c] + brw[c];
    __syncthreads();

#pragma unroll
    for (int p = 0; p < 8; p++) {
        int n = (p * 256 + t) >> 7;
        float acc = bsum;
#pragma unroll
        for (int k = 0; k < cNF; k += 4) {
            float4 s4 = *(const float4*)&sx[n][k];
            acc += s4.x * wcol[k] + s4.y * wcol[k + 1] + s4.z * wcol[k + 2] + s4.w * wcol[k + 3];
        }
#pragma unroll
        for (int k = 0; k < cRW; k += 4) {
            float4 s4 = *(const float4*)&srw[n][k];
            acc += s4.x * wrcol[k] + s4.y * wrcol[k + 1] + s4.z * wrcol[k + 2] + s4.w * wrcol[k + 3];
        }
        size_t oidx = (size_t)(nb + n) * HH + c;
        if (BF16OUT) ((unsigned short*)outv)[oidx] = f2b(acc);
        else         ((float*)outv)[oidx] = acc;
    }
}

// ---------------- ctx layer: MFMA edge-MLP (gathered A) + edge-parallel agg + bf16 MFMA GEMM ----------------
__global__ void __launch_bounds__(256)
k_layer_ctx(const unsigned short* __restrict__ h_in, unsigned short* __restrict__ h_out,
            const int* __restrict__ rp, const int* __restrict__ srcs,
            const int* __restrict__ ais,
            const float* __restrict__ eattr, const float* __restrict__ ew,
            const unsigned short* __restrict__ wez, const float* __restrict__ be,
            const unsigned short* __restrict__ Wfrag, const float* __restrict__ bias) {
    __shared__ unsigned short pool[8448];   // union: msg[64][130] | At[32][264]
    __shared__ float wsl[64];
    auto msg = (unsigned short (*)[130])pool;
    auto At  = (unsigned short (*)[264])pool;
    int t = threadIdx.x;
    int base = blockIdx.x * 32;
    int lane = t & 63, wv = t >> 6, ar = lane & 15, g4 = lane >> 4;

    // edge-MLP B-fragments + bias for this wave's 2 col-tiles
    s16x8 bez[2];
    float beq[2];
#pragma unroll
    for (int q = 0; q < 2; q++) {
        bez[q] = *(const s16x8*)&wez[((size_t)(2 * wv + q) * 64 + lane) * 8];
        beq[q] = be[(2 * wv + q) * 16 + ar];
    }
    int eblk0 = rp[base], eblk1 = rp[base + 32];
    int prow = t >> 3, pch = (t & 7) * 16;
    int re0 = rp[base + prow], re1 = rp[base + prow + 1];
    float acc[16];
#pragma unroll
    for (int j = 0; j < 16; j++) acc[j] = 0.f;

    for (int cs = eblk0; cs < eblk1; cs += 64) {
        int ce = min(cs + 64, eblk1);
        // stage per-slot edge weights
        if (t < 64) {
            int e = cs + t;
            if (e < ce) wsl[t] = ew[ais[e]];
        }
        // phase 1: edge MLP as MFMA: [64,16(pad32)] @ [16(pad32),128], A gathered via ais
        {
            f32x4 cac[4][2];
#pragma unroll
            for (int rt = 0; rt < 4; rt++)
#pragma unroll
                for (int q = 0; q < 2; q++) cac[rt][q] = (f32x4)(0.f);
#pragma unroll
            for (int rt = 0; rt < 4; rt++) {
                s16x8 af = {0, 0, 0, 0, 0, 0, 0, 0};
                int row = cs + rt * 16 + ar;
                if (g4 < 2 && row < eblk1) {
                    const float* ea = eattr + (size_t)ais[row] * cNE + g4 * 8;
                    float4 lo4 = *(const float4*)ea;
                    float4 hi4 = *(const float4*)(ea + 4);
                    af[0] = (short)f2b(lo4.x); af[1] = (short)f2b(lo4.y);
                    af[2] = (short)f2b(lo4.z); af[3] = (short)f2b(lo4.w);
                    af[4] = (short)f2b(hi4.x); af[5] = (short)f2b(hi4.y);
                    af[6] = (short)f2b(hi4.z); af[7] = (short)f2b(hi4.w);
                }
#pragma unroll
                for (int q = 0; q < 2; q++)
                    cac[rt][q] = __builtin_amdgcn_mfma_f32_16x16x32_bf16(af, bez[q], cac[rt][q], 0, 0, 0);
            }
#pragma unroll
            for (int rt = 0; rt < 4; rt++)
#pragma unroll
                for (int q = 0; q < 2; q++) {
                    int col = (2 * wv + q) * 16 + ar;
#pragma unroll
                    for (int qi = 0; qi < 4; qi++)
                        msg[rt * 16 + g4 * 4 + qi][col] = f2b(fmaxf(cac[rt][q][qi] + beq[q], 0.f));
                }
        }
        __syncthreads();
        // phase 2: thread = (row, 16-ch slice), f32 register accum
        {
            int e0 = max(re0, cs), e1 = min(re1, ce);
            for (int e = e0; e < e1; e++) {
                int sl = e - cs;
                float w = wsl[sl];
                int s = srcs[e];
                const unsigned short* hrow = &h_in[(size_t)s * HH + pch];
#pragma unroll
                for (int j = 0; j < 16; j += 2) {
                    unsigned int hv = *(const unsigned int*)&hrow[j];
                    unsigned int mv = *(const unsigned int*)&msg[sl][pch + j];
                    acc[j]     += (b2f((unsigned short)hv) + b2f((unsigned short)mv)) * w;
                    acc[j + 1] += (b2f((unsigned short)(hv >> 16)) +
                                   b2f((unsigned short)(mv >> 16))) * w;
                }
            }
        }
        __syncthreads();
    }
    // build A-tile (msg dead): agg half from registers, own-h half from global
#pragma unroll
    for (int j = 0; j < 16; j++) At[prow][HH + pch + j] = f2b(acc[j]);
    for (int i = t; i < 512; i += 256) {
        int r = i >> 4, cc = (i & 15) * 8;
        *(s16x8*)&At[r][cc] = *(const s16x8*)&h_in[(size_t)(base + r) * HH + cc];
    }
    __syncthreads();

    // layer GEMM: wave wv -> col-tiles 2wv,2wv+1; row-tiles 0,1; K=256 in 8 steps
    f32x4 ac[2][2];
#pragma unroll
    for (int i1 = 0; i1 < 2; i1++)
#pragma unroll
        for (int i2 = 0; i2 < 2; i2++) ac[i1][i2] = (f32x4)(0.f);
#pragma unroll
    for (int ks = 0; ks < 8; ks++) {
        int ak = ks * 32 + g4 * 8;
        s16x8 a0 = *(const s16x8*)&At[ar][ak];
        s16x8 a1 = *(const s16x8*)&At[16 + ar][ak];
#pragma unroll
        for (int q = 0; q < 2; q++) {
            int ct = 2 * wv + q;
            s16x8 bq = *(const s16x8*)&Wfrag[((size_t)(ct * 8 + ks) * 64 + lane) * 8];
            ac[0][q] = __builtin_amdgcn_mfma_f32_16x16x32_bf16(a0, bq, ac[0][q], 0, 0, 0);
            ac[1][q] = __builtin_amdgcn_mfma_f32_16x16x32_bf16(a1, bq, ac[1][q], 0, 0, 0);
        }
    }
#pragma unroll
    for (int rt = 0; rt < 2; rt++)
#pragma unroll
        for (int q = 0; q < 2; q++) {
            int col = (2 * wv + q) * 16 + ar;
            float bv = bias[col];
#pragma unroll
            for (int qi = 0; qi < 4; qi++) {
                int row = base + rt * 16 + g4 * 4 + qi;
                h_out[(size_t)row * HH + col] = f2b(fmaxf(ac[rt][q][qi] + bv, 0.f));
            }
        }
}

// ---------------- tgt layer: edge-parallel agg + bf16x3 MFMA GEMM (f32-accurate) ----------------
__global__ void __launch_bounds__(256)
k_layer_tgt(const float* __restrict__ h_in, float* __restrict__ h_out,
            const int* __restrict__ rp, const int* __restrict__ srcs,
            const int* __restrict__ ais,
            const float* __restrict__ eattr, const float* __restrict__ ew,
            const float* __restrict__ We, const float* __restrict__ be,
            const unsigned short* __restrict__ WfH, const unsigned short* __restrict__ WfL,
            const float* __restrict__ bias) {
    __shared__ unsigned short pool[16896];  // union: msg f32[64][129] | At_hi+At_lo
    __shared__ float WeL[16][128];
    __shared__ float beL[128];
    __shared__ float wsl[64];
    auto msg  = (float (*)[129])pool;
    auto AtH  = (unsigned short (*)[264])pool;
    auto AtL  = (unsigned short (*)[264])(pool + 8448);
    int t = threadIdx.x;
    int base = blockIdx.x * 32;

    for (int i = t; i < 2048; i += 256) WeL[i >> 7][i & 127] = We[i];
    if (t < 128) beL[t] = be[t];
    int eblk0 = rp[base], eblk1 = rp[base + 32];
    int prow = t >> 3, pch = (t & 7) * 16;
    int re0 = rp[base + prow], re1 = rp[base + prow + 1];
    float acc[16];
#pragma unroll
    for (int j = 0; j < 16; j++) acc[j] = 0.f;
    __syncthreads();

    for (int cs = eblk0; cs < eblk1; cs += 64) {
        int ce = min(cs + 64, eblk1);
        {
            int slot = t & 63, q = t >> 6;
            int e = cs + slot;
            if (e < ce) {
                int ai = ais[e];
                if (q == 0) wsl[slot] = ew[ai];
                const float* ea = eattr + (size_t)ai * cNE;
                float eav[16];
#pragma unroll
                for (int k = 0; k < 16; k += 4) *(float4*)&eav[k] = *(const float4*)&ea[k];
                int c0 = q * 32;
                float m[32];
#pragma unroll
                for (int c = 0; c < 32; c++) m[c] = beL[c0 + c];
#pragma unroll
                for (int k = 0; k < 16; k++) {
                    float ev = eav[k];
#pragma unroll
                    for (int c = 0; c < 32; c++) m[c] += ev * WeL[k][c0 + c];
                }
#pragma unroll
                for (int c = 0; c < 32; c++) msg[slot][c0 + c] = fmaxf(m[c], 0.f);
            }
        }
        __syncthreads();
        {
            int e0 = max(re0, cs), e1 = min(re1, ce);
            for (int e = e0; e < e1; e++) {
                int sl = e - cs;
                float w = wsl[sl];
                int s = srcs[e];
                const float* hrow = &h_in[(size_t)s * HH + pch];
#pragma unroll
                for (int j = 0; j < 16; j += 4) {
                    float4 hv = *(const float4*)&hrow[j];
                    acc[j]     += (hv.x + msg[sl][pch + j])     * w;
                    acc[j + 1] += (hv.y + msg[sl][pch + j + 1]) * w;
                    acc[j + 2] += (hv.z + msg[sl][pch + j + 2]) * w;
                    acc[j + 3] += (hv.w + msg[sl][pch + j + 3]) * w;
                }
            }
        }
        __syncthreads();
    }
    // build hi/lo split A-tile (msg dead)
#pragma unroll
    for (int j = 0; j < 16; j++) {
        float v = acc[j];
        unsigned short hi = f2b(v);
        AtH[prow][HH + pch + j] = hi;
        AtL[prow][HH + pch + j] = f2b(v - b2f(hi));
    }
    for (int i = t; i < 32 * HH; i += 256) {
        int r = i >> 7, c = i & 127;
        float v = h_in[(size_t)(base + r) * HH + c];
        unsigned short hi = f2b(v);
        AtH[r][c] = hi;
        AtL[r][c] = f2b(v - b2f(hi));
    }
    __syncthreads();

    // bf16x3 MFMA: acc = aH*bH + aL*bH + aH*bL
    int lane = t & 63, wv = t >> 6;
    f32x4 ac[2][2];
#pragma unroll
    for (int i1 = 0; i1 < 2; i1++)
#pragma unroll
        for (int i2 = 0; i2 < 2; i2++) ac[i1][i2] = (f32x4)(0.f);
    int ar = lane & 15, g4 = lane >> 4;
#pragma unroll
    for (int ks = 0; ks < 8; ks++) {
        int ak = ks * 32 + g4 * 8;
        s16x8 a0h = *(const s16x8*)&AtH[ar][ak];
        s16x8 a1h = *(const s16x8*)&AtH[16 + ar][ak];
        s16x8 a0l = *(const s16x8*)&AtL[ar][ak];
        s16x8 a1l = *(const s16x8*)&AtL[16 + ar][ak];
#pragma unroll
        for (int q = 0; q < 2; q++) {
            int ct = 2 * wv + q;
            size_t fo = ((size_t)(ct * 8 + ks) * 64 + lane) * 8;
            s16x8 bh = *(const s16x8*)&WfH[fo];
            s16x8 bl = *(const s16x8*)&WfL[fo];
            ac[0][q] = __builtin_amdgcn_mfma_f32_16x16x32_bf16(a0h, bh, ac[0][q], 0, 0, 0);
            ac[0][q] = __builtin_amdgcn_mfma_f32_16x16x32_bf16(a0l, bh, ac[0][q], 0, 0, 0);
            ac[0][q] = __builtin_amdgcn_mfma_f32_16x16x32_bf16(a0h, bl, ac[0][q], 0, 0, 0);
            ac[1][q] = __builtin_amdgcn_mfma_f32_16x16x32_bf16(a1h, bh, ac[1][q], 0, 0, 0);
            ac[1][q] = __builtin_amdgcn_mfma_f32_16x16x32_bf16(a1l, bh, ac[1][q], 0, 0, 0);
            ac[1][q] = __builtin_amdgcn_mfma_f32_16x16x32_bf16(a1h, bl, ac[1][q], 0, 0, 0);
        }
    }
#pragma unroll
    for (int rt = 0; rt < 2; rt++)
#pragma unroll
        for (int q = 0; q < 2; q++) {
            int col = (2 * wv + q) * 16 + ar;
            float bv = bias[col];
#pragma unroll
            for (int qi = 0; qi < 4; qi++) {
                int row = base + rt * 16 + g4 * 4 + qi;
                h_out[(size_t)row * HH + col] = fmaxf(ac[rt][q][qi] + bv, 0.f);
            }
        }
}

// ---------------- segmented mean over sorted batch ----------------
__global__ void k_seg_mean_f32(const float* __restrict__ src, const int* __restrict__ map,
                               const int* __restrict__ batch, float* __restrict__ out, int nrows) {
    int b = blockIdx.x;
    int t = threadIdx.x;  // 128
    int lo = 0, hi = nrows;
    while (lo < hi) { int m = (lo + hi) >> 1; if (batch[m] < b) lo = m + 1; else hi = m; }
    int s = lo;
    hi = nrows;
    while (lo < hi) { int m = (lo + hi) >> 1; if (batch[m] < b + 1) lo = m + 1; else hi = m; }
    int e = lo;
    float acc = 0.f;
    for (int r = s; r < e; r++) {
        size_t row = map ? (size_t)map[r] : (size_t)r;
        acc += src[row * HH + t];
    }
    out[(size_t)b * HH + t] = acc / fmaxf((float)(e - s), 1.f);
}

__global__ void k_seg_mean_bf16(const unsigned short* __restrict__ src,
                                const int* __restrict__ batch, float* __restrict__ out, int nrows) {
    int b = blockIdx.x;
    int t = threadIdx.x;  // 128
    int lo = 0, hi = nrows;
    while (lo < hi) { int m = (lo + hi) >> 1; if (batch[m] < b) lo = m + 1; else hi = m; }
    int s = lo;
    hi = nrows;
    while (lo < hi) { int m = (lo + hi) >> 1; if (batch[m] < b + 1) lo = m + 1; else hi = m; }
    int e = lo;
    float acc = 0.f;
    for (int r = s; r < e; r++) acc += b2f(src[(size_t)r * HH + t]);
    out[(size_t)b * HH + t] = acc / fmaxf((float)(e - s), 1.f);
}

// ---------------- head kernels ----------------
__global__ void k_cond(const float* __restrict__ mctx, const float* __restrict__ mtgt,
                       const int* __restrict__ cidx, const int* __restrict__ tgt_idxs,
                       const float* __restrict__ ppe, const float* __restrict__ Wprw,
                       const float* __restrict__ bprw, float* __restrict__ cond,
                       float* __restrict__ out0) {
    int r = blockIdx.x;   // 0..2047
    int t = threadIdx.x;  // 128
    int bg = r >> 2, tt = r & 3;
    int ti = tgt_idxs[bg * cPT + tt] + bg * cPPG;
    int ci = cidx[bg] + bg * cPPG;
    __shared__ float pe[cPRW];
    if (t < cPRW) pe[t] = ppe[(size_t)ti * cPRW + t];
    __syncthreads();
    float acc = bprw[t];
#pragma unroll
    for (int k = 0; k < cPRW; k++) acc += pe[k] * Wprw[k * HH + t];
    cond[(size_t)r * HH + t] = mctx[(size_t)ci * HH + t] + acc;
    out0[(size_t)r * HH + t] = mtgt[(size_t)ti * HH + t];
}

__global__ void k_gemm_h(const float* __restrict__ x, const float* __restrict__ W,
                         const float* __restrict__ b, float* __restrict__ y) {
    int r = blockIdx.x;
    int t = threadIdx.x;  // 128
    __shared__ float xr[HH];
    xr[t] = x[(size_t)r * HH + t];
    __syncthreads();
    float acc = b[t];
#pragma unroll 8
    for (int k = 0; k < HH; k++) acc += xr[k] * W[k * HH + t];
    y[(size_t)r * HH + t] = acc;
}

__global__ void k_bn_stats(const float* __restrict__ x, float* __restrict__ stats, int rows) {
    int c = blockIdx.x;
    int t = threadIdx.x;  // 256
    float s = 0.f, sq = 0.f;
    for (int r = t; r < rows; r += 256) {
        float v = x[(size_t)r * HH + c];
        s += v; sq += v * v;
    }
    __shared__ float bs[256], bq[256];
    bs[t] = s; bq[t] = sq;
    __syncthreads();
    for (int o = 128; o > 0; o >>= 1) {
        if (t < o) { bs[t] += bs[t + o]; bq[t] += bq[t + o]; }
        __syncthreads();
    }
    if (t == 0) {
        float m = bs[0] / rows;
        float var = bq[0] / rows - m * m;
        stats[c] = m;
        stats[HH + c] = rsqrtf(var + 1e-5f);
    }
}

__global__ void k_bn_relu(float* __restrict__ x, const float* __restrict__ stats,
                          const float* __restrict__ g, const float* __restrict__ be, int rows) {
    int gid = blockIdx.x * 256 + threadIdx.x;
    if (gid >= rows * HH) return;
    int c = gid & 127;
    float v = (x[gid] - stats[c]) * stats[HH + c] * g[c] + be[c];
    x[gid] = fmaxf(v, 0.f);
}

// ---------------- CSR build driver ----------------
static void build_csr(const int* src, const int* dst, const int* emap, int nnodes, int ne,
                      int* rp, int* srcs, int* ais, int* cursor, int* bsum,
                      hipStream_t stream) {
    int nb = (nnodes + 255) / 256;
    k_zero_int<<<nb, 256, 0, stream>>>(cursor, nnodes);
    k_hist<<<(ne + 255) / 256, 256, 0, stream>>>(dst, cursor, ne);
    k_scan_local<<<nb, 256, 0, stream>>>(cursor, rp + 1, bsum, nnodes);
    k_scan_bsums<<<1, 256, 0, stream>>>(bsum, nb);
    k_rp_finalize<<<nb, 256, 0, stream>>>(bsum, rp, nnodes);
    k_copy_int<<<nb, 256, 0, stream>>>(rp, cursor, nnodes);
    k_scatter<<<(ne + 255) / 256, 256, 0, stream>>>(src, dst, emap, cursor, srcs, ais, ne);
}

extern "C" void kernel_launch(void* const* d_in, const int* in_sizes, int n_in,
                              void* d_out, int out_size, void* d_ws, size_t ws_size,
                              hipStream_t stream) {
    (void)in_sizes; (void)n_in;
    const float* x      = (const float*)d_in[0];
    const float* rw     = (const float*)d_in[1];
    const int*   eidx   = (const int*)d_in[3];
    const float* eattr  = (const float*)d_in[4];
    const float* ew     = (const float*)d_in[5];
    const float* ppe    = (const float*)d_in[6];
    const int*   nmap   = (const int*)d_in[7];
    const int*   csub   = (const int*)d_in[8];
    const int*   semap  = (const int*)d_in[9];
    const int*   sbatch = (const int*)d_in[10];
    const int*   cidx   = (const int*)d_in[11];
    const int*   tgts   = (const int*)d_in[12];
    const float* Win  = (const float*)d_in[14]; const float* bin  = (const float*)d_in[15];
    const float* Wrw  = (const float*)d_in[16]; const float* brw  = (const float*)d_in[17];
    const float* Wprw = (const float*)d_in[18]; const float* bprw = (const float*)d_in[19];
    const float* cWe  = (const float*)d_in[20]; const float* cbe  = (const float*)d_in[21];
    const float* cWl  = (const float*)d_in[22]; const float* cbl  = (const float*)d_in[23];
    const float* tWe  = (const float*)d_in[24]; const float* tbe  = (const float*)d_in[25];
    const float* tWl  = (const float*)d_in[26]; const float* tbl  = (const float*)d_in[27];
    const float* Wp1  = (const float*)d_in[28]; const float* bp1  = (const float*)d_in[29];
    const float* g1   = (const float*)d_in[30]; const float* be1  = (const float*)d_in[31];
    const float* Wp2  = (const float*)d_in[32]; const float* bp2  = (const float*)d_in[33];
    const float* g2   = (const float*)d_in[34]; const float* be2  = (const float*)d_in[35];
    const float* Wp3  = (const float*)d_in[36]; const float* bp3  = (const float*)d_in[37];
    float* out = (float*)d_out;

    // ---- workspace layout (round-10 proven layout + 8KB wez) ----
    const size_t R = (size_t)cN * HH * sizeof(float);  // 102,400,000
    char* base = (char*)d_ws;
    float* R0f = (float*)base;
    float* R1f = (float*)(base + R);
    unsigned short* R0h = (unsigned short*)base;
    unsigned short* R1h = (unsigned short*)(base + R);
    int* ip = (int*)(base + 2 * R);
    int* rp_t  = ip;  ip += cN + 1;
    int* rp_c  = ip;  ip += cNS + 1;
    int* src_t = ip;  ip += cE;
    int* ai_t  = ip;  ip += cE;
    int* src_c = ip;  ip += cES;
    int* ai_c  = ip;  ip += cES;
    int* cursor = ip; ip += cNS;
    int* bsum  = ip;  ip += 2048;
    char* cp = (char*)(((uintptr_t)ip + 15) & ~(uintptr_t)15);
    unsigned short* wfragC  = (unsigned short*)cp;            // 4 x 32768
    unsigned short* wfragTH = wfragC + (size_t)4 * 32768;     // 4 x 32768
    unsigned short* wfragTL = wfragTH + (size_t)4 * 32768;    // 4 x 32768
    unsigned short* wez_c   = wfragTL + (size_t)4 * 32768;    // 4096
    cp += ((size_t)12 * 32768 + 4096) * sizeof(unsigned short);
    float* fp  = (float*)cp;
    float* mctx = fp; fp += (size_t)cNP * HH;
    float* mtgt = fp; fp += (size_t)cNP * HH;
    float* bufc = fp; fp += (size_t)2048 * HH;
    float* bufa = fp; fp += (size_t)2048 * HH;
    float* bufb = fp; fp += (size_t)2048 * HH;
    float* stats = fp; fp += 256;
    const size_t need = (size_t)((char*)fp - base);
    if (ws_size < need) {
        k_diag<<<(out_size + 255) / 256, 256, 0, stream>>>(out, out_size,
                                                           (float)(ws_size >> 20));
        return;
    }

    // ---- phase 0: CSRs + W fragments ----
    build_csr(eidx, eidx + cE, nullptr, cN, cE, rp_t, src_t, ai_t, cursor, bsum, stream);
    build_csr(csub, csub + cES, semap, cNS, cES, rp_c, src_c, ai_c, cursor, bsum, stream);
    k_wfrag_all<<<208, 256, 0, stream>>>(cWl, tWl, cWe, wfragC, wfragTH, wfragTL, wez_c);

    // ---- phase 1: target branch, f32 ping-pong R0 <-> R1 ----
    k_encode16<false><<<cN / 16, 256, 0, stream>>>(x, rw, nullptr, Win, bin, Wrw, brw, R0f);
    {
        float* hp[2] = { R0f, R1f };
        for (int l = 0; l < cL; l++) {
            k_layer_tgt<<<cN / 32, 256, 0, stream>>>(
                hp[l & 1], hp[(l & 1) ^ 1], rp_t, src_t, ai_t,
                eattr, ew, tWe, tbe,
                wfragTH + (size_t)l * 32768, wfragTL + (size_t)l * 32768, tbl + l * HH);
        }
    }
    k_seg_mean_f32<<<cNP, 128, 0, stream>>>(R0f, nmap, sbatch, mtgt, cNS);

    // ---- phase 2: context branch, bf16 ping-pong + MFMA ----
    k_encode16<true><<<cNS / 16, 256, 0, stream>>>(x, rw, nmap, Win, bin, Wrw, brw, R0h);
    {
        unsigned short* hp[2] = { R0h, R1h };
        for (int l = 0; l < cL; l++) {
            k_layer_ctx<<<cNS / 32, 256, 0, stream>>>(
                hp[l & 1], hp[(l & 1) ^ 1], rp_c, src_c, ai_c,
                eattr, ew, wez_c, cbe, wfragC + (size_t)l * 32768, cbl + l * HH);
        }
    }
    k_seg_mean_bf16<<<cNP, 128, 0, stream>>>(R0h, sbatch, mctx, cNS);

    // ---- predictor head ----
    k_cond<<<cB * cPT, 128, 0, stream>>>(mctx, mtgt, cidx, tgts, ppe, Wprw, bprw, bufc, out);
    k_gemm_h<<<2048, 128, 0, stream>>>(bufc, Wp1, bp1, bufa);
    k_bn_stats<<<HH, 256, 0, stream>>>(bufa, stats, 2048);
    k_bn_relu<<<(2048 * HH) / 256, 256, 0, stream>>>(bufa, stats, g1, be1, 2048);
    k_gemm_h<<<2048, 128, 0, stream>>>(bufa, Wp2, bp2, bufb);
    k_bn_stats<<<HH, 256, 0, stream>>>(bufb, stats, 2048);
    k_bn_relu<<<(2048 * HH) / 256, 256, 0, stream>>>(bufb, stats, g2, be2, 2048);
    k_gemm_h<<<2048, 128, 0, stream>>>(bufb, Wp3, bp3, out + (size_t)2048 * HH);
}